// Round 16
// baseline (4420.748 us; speedup 1.0000x reference)
//
#include <hip/hip_runtime.h>
#include <hip/hip_bf16.h>
#include <math.h>

namespace {

constexpr int B  = 8;
constexpr int N  = 2048;     // power of two: n = p & 2047, b = p >> 11
constexpr int K  = 20;
constexpr int C1 = 64, C2 = 128, C3 = 256;
constexpr int NSLICE = 64;
constexpr double COUNT = 327680.0;   // B*N*K
constexpr double BNEPS = 1e-5;

// ---- workspace layout (bytes) ----
constexpr size_t OFF_IDX1  = 0;                                  // B*N*K int
constexpr size_t OFF_IDX2  = OFF_IDX1 + (size_t)B*N*K*4;         // B*N*K int
constexpr size_t OFF_X1D   = OFF_IDX2 + (size_t)B*N*K*4;         // B*N*C1 f64
constexpr size_t OFF_X2D   = OFF_X1D  + (size_t)B*N*C1*8;        // B*N*C2 f64
constexpr size_t OFF_STATS = OFF_X2D  + (size_t)B*N*C2*8;        // 2*NSLICE*C3 f64
constexpr size_t OFF_MI    = OFF_STATS+ (size_t)2*NSLICE*C3*8;   // 2*C3 f64
constexpr size_t OFF_X2F   = OFF_MI   + 4096;                    // B*N*C2 f32
constexpr size_t OFF_XX2F  = OFF_X2F  + (size_t)B*N*C2*4;        // B*N f32
constexpr size_t OFF_BIG   = OFF_XX2F + (size_t)B*N*4;           // shared big region
// big region, sequential lifetimes (within proven footprint):
//   {hmax2,hmin2 f64} -> dist f32 (134.2 MB) -> {hmax3,hmin3 f32}

// ---- strict-rounding f32 helpers (block FMA contraction / reassociation) ----
__device__ __forceinline__ float fmul32(float a, float b){ return __fmul_rn(a,b); }
__device__ __forceinline__ float fadd32(float a, float b){ return __fadd_rn(a,b); }
__device__ __forceinline__ float fsub32(float a, float b){ return __fsub_rn(a,b); }

// ---- per-thread insertion top-20 on f32 (largest, ties keep lowest index) ----
__device__ __forceinline__ void insert_candidatef(float v, int j,
                                                  float (&best)[K], int (&bidx)[K]) {
  if (v > best[K-1]) {
    best[K-1] = v; bidx[K-1] = j;
    #pragma unroll
    for (int i = K-1; i >= 1; --i) {
      if (best[i] > best[i-1]) {
        float tv = best[i]; best[i] = best[i-1]; best[i-1] = tv;
        int   ti = bidx[i]; bidx[i] = bidx[i-1]; bidx[i-1] = ti;
      }
    }
  }
}

// ---- kNN on 3-D coords, numpy-f32-faithful (BIT-FROZEN) ----
__global__ __launch_bounds__(64) void knn_xyz_f32(const float* __restrict__ x,
                                                  int* __restrict__ idxo) {
  int row = blockIdx.x * 64 + threadIdx.x;   // grid = B*N/64
  int b = row >> 11, n = row & (N - 1);
  const float* xb = x + (size_t)b * N * 3;
  float xi0 = xb[(size_t)n*3], xi1 = xb[(size_t)n*3+1], xi2 = xb[(size_t)n*3+2];
  float xxi = fadd32(fadd32(fmul32(xi0,xi0), fmul32(xi1,xi1)), fmul32(xi2,xi2));
  float best[K]; int bidx[K];
  #pragma unroll
  for (int i = 0; i < K; ++i) { best[i] = -INFINITY; bidx[i] = 0; }
  for (int j = 0; j < N; ++j) {
    float a = xb[(size_t)j*3], c = xb[(size_t)j*3+1], d = xb[(size_t)j*3+2];
    float xxj   = fadd32(fadd32(fmul32(a,a), fmul32(c,c)), fmul32(d,d));
    float inner = fadd32(fadd32(fmul32(xi0,a), fmul32(xi1,c)), fmul32(xi2,d));
    float v = fsub32(fsub32(fmul32(2.f, inner), xxi), xxj);
    insert_candidatef(v, j, best, bidx);
  }
  int* o = idxo + (size_t)row * K;
  #pragma unroll
  for (int i = 0; i < K; ++i) o[i] = bidx[i];
}

// ---- x2 -> f32 copy + numpy pairwise(n=128) sum of squares (BIT-FROZEN) ----
__global__ __launch_bounds__(64) void xx2f_kernel(const double* __restrict__ x2d,
                                                  float* __restrict__ x2f,
                                                  float* __restrict__ xx2f) {
  int row = blockIdx.x * 64 + threadIdx.x;   // grid = B*N/64
  const double* src = x2d + (size_t)row * C2;
  float* dst = x2f + (size_t)row * C2;
  float sq[C2];
  #pragma unroll 8
  for (int c = 0; c < C2; ++c) {
    float v = (float)src[c];
    dst[c] = v;
    sq[c] = fmul32(v, v);
  }
  float r0=sq[0], r1=sq[1], r2=sq[2], r3=sq[3], r4=sq[4], r5=sq[5], r6=sq[6], r7=sq[7];
  #pragma unroll
  for (int i = 8; i < 128; i += 8) {
    r0 = fadd32(r0, sq[i+0]); r1 = fadd32(r1, sq[i+1]);
    r2 = fadd32(r2, sq[i+2]); r3 = fadd32(r3, sq[i+3]);
    r4 = fadd32(r4, sq[i+4]); r5 = fadd32(r5, sq[i+5]);
    r6 = fadd32(r6, sq[i+6]); r7 = fadd32(r7, sq[i+7]);
  }
  xx2f[row] = fadd32(fadd32(fadd32(r0,r1), fadd32(r2,r3)),
                     fadd32(fadd32(r4,r5), fadd32(r6,r7)));
}

// ---- all-batch neg-distance matrix, f32 sequential (BIT-FROZEN inner) ----
__global__ __launch_bounds__(256) void dist_f32_kernel(const float* __restrict__ x2f,
                                                       const float* __restrict__ xx2f,
                                                       float* __restrict__ dist) {
  int bz = blockIdx.z;
  const float* x2b  = x2f  + (size_t)bz * N * C2;
  const float* xx2b = xx2f + (size_t)bz * N;
  float* db = dist + (size_t)bz * N * N;
  int ti = blockIdx.y * 64;
  int tj = blockIdx.x * 64;
  int tid = threadIdx.x;
  int tr = tid >> 4, tc = tid & 15;
  __shared__ float A[64][9], Bm[64][9];
  float acc[4][4];
  #pragma unroll
  for (int u = 0; u < 4; ++u)
    #pragma unroll
    for (int v = 0; v < 4; ++v) acc[u][v] = 0.f;
  for (int c0 = 0; c0 < C2; c0 += 8) {
    for (int i = tid; i < 512; i += 256) {
      int r = i >> 3, c = i & 7;
      A[r][c]  = x2b[(size_t)(ti + r)*C2 + c0 + c];
      Bm[r][c] = x2b[(size_t)(tj + r)*C2 + c0 + c];
    }
    __syncthreads();
    #pragma unroll
    for (int c = 0; c < 8; ++c) {       // ascending c: exact sequential order
      float a[4], bv[4];
      #pragma unroll
      for (int u = 0; u < 4; ++u) a[u] = A[tr*4 + u][c];
      #pragma unroll
      for (int v = 0; v < 4; ++v) bv[v] = Bm[tc*4 + v][c];
      #pragma unroll
      for (int u = 0; u < 4; ++u)
        #pragma unroll
        for (int v = 0; v < 4; ++v)
          acc[u][v] = fadd32(acc[u][v], fmul32(a[u], bv[v]));
    }
    __syncthreads();
  }
  #pragma unroll
  for (int u = 0; u < 4; ++u) {
    int i = ti + tr*4 + u;
    float xxi = xx2b[i];
    #pragma unroll
    for (int v = 0; v < 4; ++v) {
      int j = tj + tc*4 + v;
      db[(size_t)i*N + j] = fsub32(fsub32(fmul32(2.f, acc[u][v]), xxi), xx2b[j]);
    }
  }
}

// ---- wave-parallel top-20 on frozen dist values (coalesced reads) ----
__global__ __launch_bounds__(256) void knn_feat_wave(const float* __restrict__ dist,
                                                     int* __restrict__ idxo) {
  int row  = blockIdx.x * 4 + (threadIdx.x >> 6);   // grid = B*N/4
  int lane = threadIdx.x & 63;
  const float* dr = dist + (size_t)row * N;
  float vals[32];
  #pragma unroll
  for (int t = 0; t < 32; ++t) vals[t] = dr[lane + (t << 6)];   // coalesced
  int* out = idxo + (size_t)row * K;
  for (int sel = 0; sel < K; ++sel) {
    float best = -INFINITY; int bt = 0;
    #pragma unroll
    for (int t = 0; t < 32; ++t)
      if (vals[t] > best) { best = vals[t]; bt = t; }
    int bcol = lane + (bt << 6);
    #pragma unroll
    for (int off = 32; off >= 1; off >>= 1) {
      float ov = __shfl_xor(best, off, 64);
      int   oc = __shfl_xor(bcol, off, 64);
      if (ov > best || (ov == best && oc < bcol)) { best = ov; bcol = oc; }
    }
    if (lane == 0) out[sel] = bcol;
    int kill = ((bcol & 63) == lane) ? (bcol >> 6) : 32;
    #pragma unroll
    for (int t = 0; t < 32; ++t) if (t == kill) vals[t] = -INFINITY;
  }
}

// ---- layer 1 (two-pass, f64): geometry + conv1 (BIT-FROZEN) ----
template<int PASS>
__global__ __launch_bounds__(64) void l1_kernel(
    const float* __restrict__ x, const float* __restrict__ nrm,
    const float* __restrict__ w1, const int* __restrict__ idx1,
    double* __restrict__ sS, double* __restrict__ sQ,
    const double* __restrict__ mid, const float* __restrict__ g1, const float* __restrict__ b1,
    double* __restrict__ x1d, float* __restrict__ out448,
    float* __restrict__ outR1, float* __restrict__ outR2) {
  int p = blockIdx.x;
  int tid = threadIdx.x;
  int b = p >> 11, n = p & (N - 1);
  __shared__ float  wl[C1 * 9];
  __shared__ double rotd[K][3];
  __shared__ double fld[K][9];
  for (int i = tid; i < C1 * 9; i += 64) wl[i] = w1[i];
  const float* xb = x + (size_t)b * N * 3;
  double nx = nrm[(size_t)p*3], ny = nrm[(size_t)p*3+1], nz = nrm[(size_t)p*3+2];
  double vx = ny, vy = -nx;
  double s = 1.0 / fmax(1.0 + nz, 1e-8);
  double vxy = vx * vy;
  double R1v[9];
  R1v[0] = 1.0 - s*(vy*vy); R1v[1] = s*vxy;           R1v[2] = vy;
  R1v[3] = s*vxy;           R1v[4] = 1.0 - s*(vx*vx); R1v[5] = -vx;
  R1v[6] = -vy;             R1v[7] = vx;              R1v[8] = 1.0 - s*(vx*vx + vy*vy);
  double xi0 = xb[(size_t)n*3], xi1 = xb[(size_t)n*3+1], xi2 = xb[(size_t)n*3+2];
  if (tid < K) {
    int j = idx1[(size_t)p*K + tid];
    double d0 = (double)xb[(size_t)j*3]   - xi0;
    double d1 = (double)xb[(size_t)j*3+1] - xi1;
    double d2 = (double)xb[(size_t)j*3+2] - xi2;
    rotd[tid][0] = R1v[0]*d0 + R1v[1]*d1 + R1v[2]*d2;
    rotd[tid][1] = R1v[3]*d0 + R1v[4]*d1 + R1v[5]*d2;
    rotd[tid][2] = R1v[6]*d0 + R1v[7]*d1 + R1v[8]*d2;
  }
  __syncthreads();
  double mx = 0.0, my = 0.0;
  #pragma unroll
  for (int k = 0; k < K; ++k) { mx += rotd[k][0]; my += rotd[k][1]; }
  mx /= 20.0; my /= 20.0;
  double r = sqrt(mx*mx + my*my);
  double ct = 1.0, st = 0.0;
  if (r > 0.0) { ct = mx / r; st = my / r; }   // cos/sin of atan2(my,mx)
  if (tid < K) {
    double r0 = rotd[tid][0], r1 = rotd[tid][1], r2 = rotd[tid][2];
    double a0 = ct*r0 + st*r1;
    double a1 = ct*r1 - st*r0;
    fld[tid][0] = a0;  fld[tid][1] = a1;   fld[tid][2] = r2;
    fld[tid][3] = a0;  fld[tid][4] = -a1;  fld[tid][5] = r2;   // xz-mirror
    fld[tid][6] = xi0; fld[tid][7] = xi1;  fld[tid][8] = xi2;  // x_rep
  }
  if (PASS == 0 && tid == 0) {
    float* o1 = outR1 + (size_t)p * 9;
    #pragma unroll
    for (int i = 0; i < 9; ++i) o1[i] = (float)R1v[i];
    float* o2 = outR2 + (size_t)p * 9;
    o2[0] = (float)ct;  o2[1] = (float)st; o2[2] = 0.f;
    o2[3] = (float)-st; o2[4] = (float)ct; o2[5] = 0.f;
    o2[6] = 0.f;        o2[7] = 0.f;       o2[8] = 1.f;
  }
  __syncthreads();
  int o = tid;
  if (PASS == 0) {
    double sum = 0., sq = 0.;
    #pragma unroll
    for (int k = 0; k < K; ++k) {
      double h = 0.;
      #pragma unroll
      for (int c = 0; c < 9; ++c) h = fma((double)wl[o*9 + c], fld[k][c], h);
      sum += h; sq += h*h;
    }
    int slice = p & (NSLICE - 1);
    atomicAdd(&sS[slice*C3 + o], sum);
    atomicAdd(&sQ[slice*C3 + o], sq);
  } else {
    double m = mid[o], is = mid[C3 + o];
    double g = g1[o], bb = b1[o];
    double mxv = -INFINITY;
    #pragma unroll
    for (int k = 0; k < K; ++k) {
      double h = 0.;
      #pragma unroll
      for (int c = 0; c < 9; ++c) h = fma((double)wl[o*9 + c], fld[k][c], h);
      double y = ((h - m) * is) * g + bb;
      y = y > 0.0 ? y : 0.2 * y;
      mxv = fmax(mxv, y);
    }
    x1d[(size_t)p*C1 + o] = mxv;
    out448[(size_t)p*448 + o] = (float)mxv;
  }
}

// ---- conv2 pass0, wave-k-split: wave g handles k in [10g,10g+10) for 2 o's
// (o=lane, lane+64). Per-(o,k) fma chain identical to r12 (phase1 diff c
// ascending, phase2 xrep c ascending). Stats fold made EXACTLY sequential via
// cross-wave handoff (wave0 folds k0..9, wave1 continues) -> bit-identical. ----
__global__ __launch_bounds__(128, 1) void conv2_p0(
    const double* __restrict__ x1d, const int* __restrict__ idx,
    const float* __restrict__ w,
    double* __restrict__ sS, double* __restrict__ sQ,
    double* __restrict__ hmx2, double* __restrict__ hmn2) {
  int p = blockIdx.x;
  int tid = threadIdx.x;
  int lane = tid & 63;
  int kg = tid >> 6;          // wave = k-group
  int b = p >> 11;
  __shared__ double difL[K][C1];
  __shared__ double xiL[C1];
  __shared__ int jidx[K];
  __shared__ double hs[C2], hq[C2], hm[C2], hn[C2];
  if (tid < K) jidx[tid] = idx[(size_t)p*K + tid];
  if (tid < C1) xiL[tid] = x1d[(size_t)p*C1 + tid];
  __syncthreads();
  #pragma unroll 1
  for (int i = tid; i < K*C1; i += 128) {
    int k = i >> 6, c = i & 63;
    difL[k][c] = x1d[((size_t)b*N + jidx[k])*C1 + c] - xiL[c];
  }
  __syncthreads();
  int o0 = lane, o1 = lane + 64;
  const float* wr0 = w + (size_t)o0 * (2*C1);
  const float* wr1 = w + (size_t)o1 * (2*C1);
  double a0[10], a1[10];
  #pragma unroll
  for (int kk = 0; kk < 10; ++kk) { a0[kk] = 0.0; a1[kk] = 0.0; }
  // phase 1: diff operand, c ascending per acc
  #pragma unroll 1
  for (int c0 = 0; c0 < C1; c0 += 8) {
    double w0[8], w1v[8];
    #pragma unroll
    for (int i = 0; i < 8; ++i) { w0[i] = (double)wr0[c0+i]; w1v[i] = (double)wr1[c0+i]; }
    #pragma unroll
    for (int kk = 0; kk < 10; ++kk) {
      const double* dk = difL[kg*10 + kk];
      double dv[8];
      #pragma unroll
      for (int i = 0; i < 8; ++i) dv[i] = dk[c0+i];
      #pragma unroll
      for (int i = 0; i < 8; ++i) a0[kk] = fma(w0[i], dv[i], a0[kk]);
      #pragma unroll
      for (int i = 0; i < 8; ++i) a1[kk] = fma(w1v[i], dv[i], a1[kk]);
    }
  }
  // phase 2: x_rep operand, c ascending per acc
  #pragma unroll 1
  for (int c0 = 0; c0 < C1; c0 += 8) {
    double w0[8], w1v[8], xv[8];
    #pragma unroll
    for (int i = 0; i < 8; ++i) {
      w0[i] = (double)wr0[C1+c0+i]; w1v[i] = (double)wr1[C1+c0+i]; xv[i] = xiL[c0+i];
    }
    #pragma unroll
    for (int kk = 0; kk < 10; ++kk) {
      #pragma unroll
      for (int i = 0; i < 8; ++i) a0[kk] = fma(w0[i], xv[i], a0[kk]);
      #pragma unroll
      for (int i = 0; i < 8; ++i) a1[kk] = fma(w1v[i], xv[i], a1[kk]);
    }
  }
  // exact sequential fold via handoff
  if (kg == 0) {
    double s0 = 0., q0 = 0., s1 = 0., q1 = 0.;
    double m0 = -INFINITY, n0 = INFINITY, m1 = -INFINITY, n1 = INFINITY;
    #pragma unroll
    for (int kk = 0; kk < 10; ++kk) {
      s0 += a0[kk]; q0 += a0[kk]*a0[kk];
      m0 = fmax(m0, a0[kk]); n0 = fmin(n0, a0[kk]);
      s1 += a1[kk]; q1 += a1[kk]*a1[kk];
      m1 = fmax(m1, a1[kk]); n1 = fmin(n1, a1[kk]);
    }
    hs[o0] = s0; hq[o0] = q0; hm[o0] = m0; hn[o0] = n0;
    hs[o1] = s1; hq[o1] = q1; hm[o1] = m1; hn[o1] = n1;
  }
  __syncthreads();
  if (kg == 1) {
    double s0 = hs[o0], q0 = hq[o0], s1 = hs[o1], q1 = hq[o1];
    double m0 = hm[o0], n0 = hn[o0], m1 = hm[o1], n1 = hn[o1];
    #pragma unroll
    for (int kk = 0; kk < 10; ++kk) {
      s0 += a0[kk]; q0 += a0[kk]*a0[kk];
      m0 = fmax(m0, a0[kk]); n0 = fmin(n0, a0[kk]);
      s1 += a1[kk]; q1 += a1[kk]*a1[kk];
      m1 = fmax(m1, a1[kk]); n1 = fmin(n1, a1[kk]);
    }
    hmx2[(size_t)p*C2 + o0] = m0; hmn2[(size_t)p*C2 + o0] = n0;
    hmx2[(size_t)p*C2 + o1] = m1; hmn2[(size_t)p*C2 + o1] = n1;
    int slice = p & (NSLICE - 1);
    atomicAdd(&sS[slice*C3 + o0], s0);
    atomicAdd(&sQ[slice*C3 + o0], q0);
    atomicAdd(&sS[slice*C3 + o1], s1);
    atomicAdd(&sQ[slice*C3 + o1], q1);
  }
}

// ---- conv2 pass1 (light): BN+LReLU at h extremes (monotone => exact) ----
__global__ __launch_bounds__(256) void conv2_p1_light(
    const double* __restrict__ hmx2, const double* __restrict__ hmn2,
    const double* __restrict__ mid, const float* __restrict__ gam,
    const float* __restrict__ bet,
    double* __restrict__ x2d, float* __restrict__ out448) {
  int i = blockIdx.x * 256 + threadIdx.x;   // grid = B*N*C2/256
  int p = i >> 7, o = i & 127;
  double m = mid[o], is = mid[C3 + o];
  double g = gam[o], bb = bet[o];
  double y1 = ((hmx2[i] - m) * is) * g + bb;
  y1 = y1 > 0.0 ? y1 : 0.2 * y1;
  double y2 = ((hmn2[i] - m) * is) * g + bb;
  y2 = y2 > 0.0 ? y2 : 0.2 * y2;
  double mxv = fmax(y1, y2);
  x2d[i] = mxv;
  out448[(size_t)p*448 + C1 + o] = (float)mxv;
}

// ---- conv3 pass0, wave-split: wave wv -> (kg=wv>>1, oh=wv&1). Thread does
// 2 o's (lane+128*oh, +64) x 10 k's. Per-(o,k) fmaf chain = r12 (base, then
// c ascending). Stats exact via kg0->kg1 handoff; max/min order-free. ----
__global__ __launch_bounds__(256, 1) void conv3_p0(
    const float* __restrict__ x2f, const int* __restrict__ idx,
    const float* __restrict__ w,
    double* __restrict__ sS, double* __restrict__ sQ,
    float* __restrict__ hmx3, float* __restrict__ hmn3) {
  int p = blockIdx.x;
  int tid = threadIdx.x;
  int lane = tid & 63;
  int wv = tid >> 6;
  int kg = wv >> 1;
  int oh = wv & 1;
  int b = p >> 11;
  __shared__ float xjL[K][C2];
  __shared__ float xiL[C2];
  __shared__ int jidx[K];
  __shared__ double hs[C3], hq[C3];
  __shared__ float hm[C3], hn[C3];
  if (tid < K) jidx[tid] = idx[(size_t)p*K + tid];
  if (tid < C2) xiL[tid] = x2f[(size_t)p*C2 + tid];
  __syncthreads();
  #pragma unroll 1
  for (int i = tid; i < K*C2; i += 256) {
    int k = i >> 7, c = i & 127;
    xjL[k][c] = x2f[((size_t)b*N + jidx[k])*C2 + c];
  }
  __syncthreads();
  int o0 = lane + (oh << 7);
  int o1 = o0 + 64;
  const float* wr0 = w + (size_t)o0 * (2*C2);
  const float* wr1 = w + (size_t)o1 * (2*C2);
  float base0 = 0.f, base1 = 0.f;
  #pragma unroll 1
  for (int c0 = 0; c0 < C2; c0 += 32) {
    #pragma unroll
    for (int i = 0; i < 32; ++i) {
      float xv = xiL[c0+i];
      base0 = fmaf(wr0[C2+c0+i] - wr0[c0+i], xv, base0);
      base1 = fmaf(wr1[C2+c0+i] - wr1[c0+i], xv, base1);
    }
  }
  float a0[10], a1[10];
  #pragma unroll
  for (int kk = 0; kk < 10; ++kk) { a0[kk] = base0; a1[kk] = base1; }
  #pragma unroll 1
  for (int c0 = 0; c0 < C2; c0 += 8) {
    float w0[8], w1v[8];
    #pragma unroll
    for (int i = 0; i < 8; ++i) { w0[i] = wr0[c0+i]; w1v[i] = wr1[c0+i]; }
    #pragma unroll
    for (int kk = 0; kk < 10; ++kk) {
      const float* xk = xjL[kg*10 + kk];
      float xv[8];
      #pragma unroll
      for (int i = 0; i < 8; ++i) xv[i] = xk[c0+i];
      #pragma unroll
      for (int i = 0; i < 8; ++i) a0[kk] = fmaf(w0[i], xv[i], a0[kk]);
      #pragma unroll
      for (int i = 0; i < 8; ++i) a1[kk] = fmaf(w1v[i], xv[i], a1[kk]);
    }
  }
  // exact sequential f64 fold via handoff (kg0: k0..9; kg1 continues k10..19)
  if (kg == 0) {
    double s0 = 0., q0 = 0., s1 = 0., q1 = 0.;
    float m0 = -INFINITY, n0 = INFINITY, m1 = -INFINITY, n1 = INFINITY;
    #pragma unroll
    for (int kk = 0; kk < 10; ++kk) {
      double h0 = (double)a0[kk]; s0 += h0; q0 += h0*h0;
      m0 = fmaxf(m0, a0[kk]); n0 = fminf(n0, a0[kk]);
      double h1 = (double)a1[kk]; s1 += h1; q1 += h1*h1;
      m1 = fmaxf(m1, a1[kk]); n1 = fminf(n1, a1[kk]);
    }
    hs[o0] = s0; hq[o0] = q0; hm[o0] = m0; hn[o0] = n0;
    hs[o1] = s1; hq[o1] = q1; hm[o1] = m1; hn[o1] = n1;
  }
  __syncthreads();
  if (kg == 1) {
    double s0 = hs[o0], q0 = hq[o0], s1 = hs[o1], q1 = hq[o1];
    float m0 = hm[o0], n0 = hn[o0], m1 = hm[o1], n1 = hn[o1];
    #pragma unroll
    for (int kk = 0; kk < 10; ++kk) {
      double h0 = (double)a0[kk]; s0 += h0; q0 += h0*h0;
      m0 = fmaxf(m0, a0[kk]); n0 = fminf(n0, a0[kk]);
      double h1 = (double)a1[kk]; s1 += h1; q1 += h1*h1;
      m1 = fmaxf(m1, a1[kk]); n1 = fminf(n1, a1[kk]);
    }
    hmx3[(size_t)p*C3 + o0] = m0; hmn3[(size_t)p*C3 + o0] = n0;
    hmx3[(size_t)p*C3 + o1] = m1; hmn3[(size_t)p*C3 + o1] = n1;
    int slice = p & (NSLICE - 1);
    atomicAdd(&sS[slice*C3 + o0], s0);
    atomicAdd(&sQ[slice*C3 + o0], q0);
    atomicAdd(&sS[slice*C3 + o1], s1);
    atomicAdd(&sQ[slice*C3 + o1], q1);
  }
}

// ---- conv3 pass1 (light): BN+LReLU at extremes, fmax -> out ----
__global__ __launch_bounds__(256) void conv3_p1_light(
    const float* __restrict__ hmx3, const float* __restrict__ hmn3,
    const double* __restrict__ mid, const float* __restrict__ gam,
    const float* __restrict__ bet, float* __restrict__ out448) {
  int i = blockIdx.x * 256 + threadIdx.x;   // grid = B*N*C3/256
  int p = i >> 8, o = i & 255;
  float m = (float)mid[o], is = (float)mid[C3 + o];
  float g = gam[o], bb = bet[o];
  float y1 = (hmx3[i] - m) * is * g + bb;
  y1 = y1 > 0.f ? y1 : 0.2f * y1;
  float y2 = (hmn3[i] - m) * is * g + bb;
  y2 = y2 > 0.f ? y2 : 0.2f * y2;
  out448[(size_t)p*448 + C1 + C2 + o] = fmaxf(y1, y2);
}

// ---- finalize BN stats (f64) ----
__global__ void finalize_stats(const double* __restrict__ sS, const double* __restrict__ sQ,
                               double* __restrict__ mid, int C) {
  int o = threadIdx.x;
  if (o >= C) return;
  double s = 0., q = 0.;
  for (int i = 0; i < NSLICE; ++i) { s += sS[i*C3 + o]; q += sQ[i*C3 + o]; }
  double m = s / COUNT;
  double v = q / COUNT - m*m;
  mid[o] = m;
  mid[C3 + o] = 1.0 / sqrt(v + BNEPS);
}

} // namespace

extern "C" void kernel_launch(void* const* d_in, const int* in_sizes, int n_in,
                              void* d_out, int out_size, void* d_ws, size_t ws_size,
                              hipStream_t stream) {
  (void)in_sizes; (void)n_in; (void)out_size; (void)ws_size;
  const float* x   = (const float*)d_in[0];
  const float* nrm = (const float*)d_in[1];
  const float* w1  = (const float*)d_in[2];
  const float* g1  = (const float*)d_in[3];
  const float* b1  = (const float*)d_in[4];
  const float* w2  = (const float*)d_in[5];
  const float* g2  = (const float*)d_in[6];
  const float* b2  = (const float*)d_in[7];
  const float* w3  = (const float*)d_in[8];
  const float* g3  = (const float*)d_in[9];
  const float* b3  = (const float*)d_in[10];
  float* out = (float*)d_out;
  char*  ws  = (char*)d_ws;

  int*    idx1 = (int*)(ws + OFF_IDX1);
  int*    idx2 = (int*)(ws + OFF_IDX2);
  double* x1d  = (double*)(ws + OFF_X1D);
  double* x2d  = (double*)(ws + OFF_X2D);
  double* sS   = (double*)(ws + OFF_STATS);
  double* sQ   = sS + (size_t)NSLICE * C3;
  double* mid  = (double*)(ws + OFF_MI);
  float*  x2f  = (float*)(ws + OFF_X2F);
  float*  xx2f = (float*)(ws + OFF_XX2F);
  char*   big  = ws + OFF_BIG;
  double* hmx2 = (double*)big;                                   // conv2_p0..p1
  double* hmn2 = hmx2 + (size_t)B*N*C2;
  float*  dist = (float*)big;                                    // dist..knn_feat
  float*  hmx3 = (float*)big;                                    // conv3_p0..p1
  float*  hmn3 = hmx3 + (size_t)B*N*C3;

  float* outR1 = out + (size_t)B * N * 448;
  float* outR2 = outR1 + (size_t)B * N * 9;

  // kNN1 — numpy-f32-faithful formula
  knn_xyz_f32<<<B*N/64, 64, 0, stream>>>(x, idx1);

  // layer 1 (f64 two-pass)
  hipMemsetAsync(sS, 0, (size_t)2*NSLICE*C3*sizeof(double), stream);
  l1_kernel<0><<<B*N, 64, 0, stream>>>(x, nrm, w1, idx1, sS, sQ, nullptr, nullptr, nullptr,
                                       nullptr, nullptr, outR1, outR2);
  finalize_stats<<<1, C3, 0, stream>>>(sS, sQ, mid, C1);
  l1_kernel<1><<<B*N, 64, 0, stream>>>(x, nrm, w1, idx1, nullptr, nullptr, mid, g1, b1,
                                       x1d, out, outR1, outR2);

  // layer 2: conv once (wave-k-split, exact handoff) + light BN finish
  hipMemsetAsync(sS, 0, (size_t)2*NSLICE*C3*sizeof(double), stream);
  conv2_p0<<<B*N, 128, 0, stream>>>(x1d, idx1, w2, sS, sQ, hmx2, hmn2);
  finalize_stats<<<1, C3, 0, stream>>>(sS, sQ, mid, C2);
  conv2_p1_light<<<B*N*C2/256, 256, 0, stream>>>(hmx2, hmn2, mid, g2, b2, x2d, out);

  // kNN2 — numpy-f32-faithful, all batches fused; wave-parallel coalesced top-k
  xx2f_kernel<<<B*N/64, 64, 0, stream>>>(x2d, x2f, xx2f);
  dist_f32_kernel<<<dim3(N/64, N/64, B), 256, 0, stream>>>(x2f, xx2f, dist);
  knn_feat_wave<<<B*N/4, 256, 0, stream>>>(dist, idx2);

  // layer 3: conv once (wave-split, exact handoff) + light BN finish
  hipMemsetAsync(sS, 0, (size_t)2*NSLICE*C3*sizeof(double), stream);
  conv3_p0<<<B*N, 256, 0, stream>>>(x2f, idx2, w3, sS, sQ, hmx3, hmn3);
  finalize_stats<<<1, C3, 0, stream>>>(sS, sQ, mid, C3);
  conv3_p1_light<<<B*N*C3/256, 256, 0, stream>>>(hmx3, hmn3, mid, g3, b3, out);
}

// Round 17
// 3106.675 us; speedup vs baseline: 1.4230x; 1.4230x over previous
//
#include <hip/hip_runtime.h>
#include <hip/hip_bf16.h>
#include <math.h>

namespace {

constexpr int B  = 8;
constexpr int N  = 2048;     // power of two: n = p & 2047, b = p >> 11
constexpr int K  = 20;
constexpr int C1 = 64, C2 = 128, C3 = 256;
constexpr int NSLICE = 64;
constexpr double COUNT = 327680.0;   // B*N*K
constexpr double BNEPS = 1e-5;

// ---- workspace layout (bytes) ----
constexpr size_t OFF_IDX1  = 0;                                  // B*N*K int
constexpr size_t OFF_IDX2  = OFF_IDX1 + (size_t)B*N*K*4;         // B*N*K int
constexpr size_t OFF_X1D   = OFF_IDX2 + (size_t)B*N*K*4;         // B*N*C1 f64
constexpr size_t OFF_X2D   = OFF_X1D  + (size_t)B*N*C1*8;        // B*N*C2 f64
constexpr size_t OFF_STATS = OFF_X2D  + (size_t)B*N*C2*8;        // 2*NSLICE*C3 f64
constexpr size_t OFF_MI    = OFF_STATS+ (size_t)2*NSLICE*C3*8;   // 2*C3 f64
constexpr size_t OFF_X2F   = OFF_MI   + 4096;                    // B*N*C2 f32
constexpr size_t OFF_XX2F  = OFF_X2F  + (size_t)B*N*C2*4;        // B*N f32
constexpr size_t OFF_BIG   = OFF_XX2F + (size_t)B*N*4;           // shared big region
// big region, sequential lifetimes (within proven footprint):
//   {hmax2,hmin2 f64: 33.6MB} -> dist f32 (134.2MB) -> {hmax3/hmin3 2-plane f32: 134.2MB}

// ---- strict-rounding f32 helpers (block FMA contraction / reassociation) ----
__device__ __forceinline__ float fmul32(float a, float b){ return __fmul_rn(a,b); }
__device__ __forceinline__ float fadd32(float a, float b){ return __fadd_rn(a,b); }
__device__ __forceinline__ float fsub32(float a, float b){ return __fsub_rn(a,b); }

// ---- per-thread insertion top-20 on f32 (largest, ties keep lowest index) ----
__device__ __forceinline__ void insert_candidatef(float v, int j,
                                                  float (&best)[K], int (&bidx)[K]) {
  if (v > best[K-1]) {
    best[K-1] = v; bidx[K-1] = j;
    #pragma unroll
    for (int i = K-1; i >= 1; --i) {
      if (best[i] > best[i-1]) {
        float tv = best[i]; best[i] = best[i-1]; best[i-1] = tv;
        int   ti = bidx[i]; bidx[i] = bidx[i-1]; bidx[i-1] = ti;
      }
    }
  }
}

// ---- kNN on 3-D coords, numpy-f32-faithful (BIT-FROZEN) ----
__global__ __launch_bounds__(64) void knn_xyz_f32(const float* __restrict__ x,
                                                  int* __restrict__ idxo) {
  int row = blockIdx.x * 64 + threadIdx.x;   // grid = B*N/64
  int b = row >> 11, n = row & (N - 1);
  const float* xb = x + (size_t)b * N * 3;
  float xi0 = xb[(size_t)n*3], xi1 = xb[(size_t)n*3+1], xi2 = xb[(size_t)n*3+2];
  float xxi = fadd32(fadd32(fmul32(xi0,xi0), fmul32(xi1,xi1)), fmul32(xi2,xi2));
  float best[K]; int bidx[K];
  #pragma unroll
  for (int i = 0; i < K; ++i) { best[i] = -INFINITY; bidx[i] = 0; }
  for (int j = 0; j < N; ++j) {
    float a = xb[(size_t)j*3], c = xb[(size_t)j*3+1], d = xb[(size_t)j*3+2];
    float xxj   = fadd32(fadd32(fmul32(a,a), fmul32(c,c)), fmul32(d,d));
    float inner = fadd32(fadd32(fmul32(xi0,a), fmul32(xi1,c)), fmul32(xi2,d));
    float v = fsub32(fsub32(fmul32(2.f, inner), xxi), xxj);
    insert_candidatef(v, j, best, bidx);
  }
  int* o = idxo + (size_t)row * K;
  #pragma unroll
  for (int i = 0; i < K; ++i) o[i] = bidx[i];
}

// ---- x2 -> f32 copy + numpy pairwise(n=128) sum of squares (BIT-FROZEN) ----
__global__ __launch_bounds__(64) void xx2f_kernel(const double* __restrict__ x2d,
                                                  float* __restrict__ x2f,
                                                  float* __restrict__ xx2f) {
  int row = blockIdx.x * 64 + threadIdx.x;   // grid = B*N/64
  const double* src = x2d + (size_t)row * C2;
  float* dst = x2f + (size_t)row * C2;
  float sq[C2];
  #pragma unroll 8
  for (int c = 0; c < C2; ++c) {
    float v = (float)src[c];
    dst[c] = v;
    sq[c] = fmul32(v, v);
  }
  float r0=sq[0], r1=sq[1], r2=sq[2], r3=sq[3], r4=sq[4], r5=sq[5], r6=sq[6], r7=sq[7];
  #pragma unroll
  for (int i = 8; i < 128; i += 8) {
    r0 = fadd32(r0, sq[i+0]); r1 = fadd32(r1, sq[i+1]);
    r2 = fadd32(r2, sq[i+2]); r3 = fadd32(r3, sq[i+3]);
    r4 = fadd32(r4, sq[i+4]); r5 = fadd32(r5, sq[i+5]);
    r6 = fadd32(r6, sq[i+6]); r7 = fadd32(r7, sq[i+7]);
  }
  xx2f[row] = fadd32(fadd32(fadd32(r0,r1), fadd32(r2,r3)),
                     fadd32(fadd32(r4,r5), fadd32(r6,r7)));
}

// ---- all-batch neg-distance matrix, f32 sequential (BIT-FROZEN inner) ----
__global__ __launch_bounds__(256) void dist_f32_kernel(const float* __restrict__ x2f,
                                                       const float* __restrict__ xx2f,
                                                       float* __restrict__ dist) {
  int bz = blockIdx.z;
  const float* x2b  = x2f  + (size_t)bz * N * C2;
  const float* xx2b = xx2f + (size_t)bz * N;
  float* db = dist + (size_t)bz * N * N;
  int ti = blockIdx.y * 64;
  int tj = blockIdx.x * 64;
  int tid = threadIdx.x;
  int tr = tid >> 4, tc = tid & 15;
  __shared__ float A[64][9], Bm[64][9];
  float acc[4][4];
  #pragma unroll
  for (int u = 0; u < 4; ++u)
    #pragma unroll
    for (int v = 0; v < 4; ++v) acc[u][v] = 0.f;
  for (int c0 = 0; c0 < C2; c0 += 8) {
    for (int i = tid; i < 512; i += 256) {
      int r = i >> 3, c = i & 7;
      A[r][c]  = x2b[(size_t)(ti + r)*C2 + c0 + c];
      Bm[r][c] = x2b[(size_t)(tj + r)*C2 + c0 + c];
    }
    __syncthreads();
    #pragma unroll
    for (int c = 0; c < 8; ++c) {       // ascending c: exact sequential order
      float a[4], bv[4];
      #pragma unroll
      for (int u = 0; u < 4; ++u) a[u] = A[tr*4 + u][c];
      #pragma unroll
      for (int v = 0; v < 4; ++v) bv[v] = Bm[tc*4 + v][c];
      #pragma unroll
      for (int u = 0; u < 4; ++u)
        #pragma unroll
        for (int v = 0; v < 4; ++v)
          acc[u][v] = fadd32(acc[u][v], fmul32(a[u], bv[v]));
    }
    __syncthreads();
  }
  #pragma unroll
  for (int u = 0; u < 4; ++u) {
    int i = ti + tr*4 + u;
    float xxi = xx2b[i];
    #pragma unroll
    for (int v = 0; v < 4; ++v) {
      int j = tj + tc*4 + v;
      db[(size_t)i*N + j] = fsub32(fsub32(fmul32(2.f, acc[u][v]), xxi), xx2b[j]);
    }
  }
}

// ---- wave-parallel top-20 on frozen dist values (coalesced reads) ----
__global__ __launch_bounds__(256) void knn_feat_wave(const float* __restrict__ dist,
                                                     int* __restrict__ idxo) {
  int row  = blockIdx.x * 4 + (threadIdx.x >> 6);   // grid = B*N/4
  int lane = threadIdx.x & 63;
  const float* dr = dist + (size_t)row * N;
  float vals[32];
  #pragma unroll
  for (int t = 0; t < 32; ++t) vals[t] = dr[lane + (t << 6)];   // coalesced
  int* out = idxo + (size_t)row * K;
  for (int sel = 0; sel < K; ++sel) {
    float best = -INFINITY; int bt = 0;
    #pragma unroll
    for (int t = 0; t < 32; ++t)
      if (vals[t] > best) { best = vals[t]; bt = t; }
    int bcol = lane + (bt << 6);
    #pragma unroll
    for (int off = 32; off >= 1; off >>= 1) {
      float ov = __shfl_xor(best, off, 64);
      int   oc = __shfl_xor(bcol, off, 64);
      if (ov > best || (ov == best && oc < bcol)) { best = ov; bcol = oc; }
    }
    if (lane == 0) out[sel] = bcol;
    int kill = ((bcol & 63) == lane) ? (bcol >> 6) : 32;
    #pragma unroll
    for (int t = 0; t < 32; ++t) if (t == kill) vals[t] = -INFINITY;
  }
}

// ---- layer 1 (two-pass, f64): geometry + conv1 (BIT-FROZEN) ----
template<int PASS>
__global__ __launch_bounds__(64) void l1_kernel(
    const float* __restrict__ x, const float* __restrict__ nrm,
    const float* __restrict__ w1, const int* __restrict__ idx1,
    double* __restrict__ sS, double* __restrict__ sQ,
    const double* __restrict__ mid, const float* __restrict__ g1, const float* __restrict__ b1,
    double* __restrict__ x1d, float* __restrict__ out448,
    float* __restrict__ outR1, float* __restrict__ outR2) {
  int p = blockIdx.x;
  int tid = threadIdx.x;
  int b = p >> 11, n = p & (N - 1);
  __shared__ float  wl[C1 * 9];
  __shared__ double rotd[K][3];
  __shared__ double fld[K][9];
  for (int i = tid; i < C1 * 9; i += 64) wl[i] = w1[i];
  const float* xb = x + (size_t)b * N * 3;
  double nx = nrm[(size_t)p*3], ny = nrm[(size_t)p*3+1], nz = nrm[(size_t)p*3+2];
  double vx = ny, vy = -nx;
  double s = 1.0 / fmax(1.0 + nz, 1e-8);
  double vxy = vx * vy;
  double R1v[9];
  R1v[0] = 1.0 - s*(vy*vy); R1v[1] = s*vxy;           R1v[2] = vy;
  R1v[3] = s*vxy;           R1v[4] = 1.0 - s*(vx*vx); R1v[5] = -vx;
  R1v[6] = -vy;             R1v[7] = vx;              R1v[8] = 1.0 - s*(vx*vx + vy*vy);
  double xi0 = xb[(size_t)n*3], xi1 = xb[(size_t)n*3+1], xi2 = xb[(size_t)n*3+2];
  if (tid < K) {
    int j = idx1[(size_t)p*K + tid];
    double d0 = (double)xb[(size_t)j*3]   - xi0;
    double d1 = (double)xb[(size_t)j*3+1] - xi1;
    double d2 = (double)xb[(size_t)j*3+2] - xi2;
    rotd[tid][0] = R1v[0]*d0 + R1v[1]*d1 + R1v[2]*d2;
    rotd[tid][1] = R1v[3]*d0 + R1v[4]*d1 + R1v[5]*d2;
    rotd[tid][2] = R1v[6]*d0 + R1v[7]*d1 + R1v[8]*d2;
  }
  __syncthreads();
  double mx = 0.0, my = 0.0;
  #pragma unroll
  for (int k = 0; k < K; ++k) { mx += rotd[k][0]; my += rotd[k][1]; }
  mx /= 20.0; my /= 20.0;
  double r = sqrt(mx*mx + my*my);
  double ct = 1.0, st = 0.0;
  if (r > 0.0) { ct = mx / r; st = my / r; }   // cos/sin of atan2(my,mx)
  if (tid < K) {
    double r0 = rotd[tid][0], r1 = rotd[tid][1], r2 = rotd[tid][2];
    double a0 = ct*r0 + st*r1;
    double a1 = ct*r1 - st*r0;
    fld[tid][0] = a0;  fld[tid][1] = a1;   fld[tid][2] = r2;
    fld[tid][3] = a0;  fld[tid][4] = -a1;  fld[tid][5] = r2;   // xz-mirror
    fld[tid][6] = xi0; fld[tid][7] = xi1;  fld[tid][8] = xi2;  // x_rep
  }
  if (PASS == 0 && tid == 0) {
    float* o1 = outR1 + (size_t)p * 9;
    #pragma unroll
    for (int i = 0; i < 9; ++i) o1[i] = (float)R1v[i];
    float* o2 = outR2 + (size_t)p * 9;
    o2[0] = (float)ct;  o2[1] = (float)st; o2[2] = 0.f;
    o2[3] = (float)-st; o2[4] = (float)ct; o2[5] = 0.f;
    o2[6] = 0.f;        o2[7] = 0.f;       o2[8] = 1.f;
  }
  __syncthreads();
  int o = tid;
  if (PASS == 0) {
    double sum = 0., sq = 0.;
    #pragma unroll
    for (int k = 0; k < K; ++k) {
      double h = 0.;
      #pragma unroll
      for (int c = 0; c < 9; ++c) h = fma((double)wl[o*9 + c], fld[k][c], h);
      sum += h; sq += h*h;
    }
    int slice = p & (NSLICE - 1);
    atomicAdd(&sS[slice*C3 + o], sum);
    atomicAdd(&sQ[slice*C3 + o], sq);
  } else {
    double m = mid[o], is = mid[C3 + o];
    double g = g1[o], bb = b1[o];
    double mxv = -INFINITY;
    #pragma unroll
    for (int k = 0; k < K; ++k) {
      double h = 0.;
      #pragma unroll
      for (int c = 0; c < 9; ++c) h = fma((double)wl[o*9 + c], fld[k][c], h);
      double y = ((h - m) * is) * g + bb;
      y = y > 0.0 ? y : 0.2 * y;
      mxv = fmax(mxv, y);
    }
    x1d[(size_t)p*C1 + o] = mxv;
    out448[(size_t)p*448 + o] = (float)mxv;
  }
}

// ---- conv2 core: r12-proven LDS op sequence, 128 threads (BIT-FROZEN) ----
__device__ __forceinline__ void conv2_core(const double* __restrict__ x1d,
                                           const int* __restrict__ idx,
                                           const float* __restrict__ w,
                                           int p, int tid, double (&acc)[K]) {
  int b = p >> 11;
  __shared__ double difL[K][C1];
  __shared__ double xiL[C1];
  __shared__ int jidx[K];
  if (tid < K) jidx[tid] = idx[(size_t)p*K + tid];
  if (tid < C1) xiL[tid] = x1d[(size_t)p*C1 + tid];
  __syncthreads();
  #pragma unroll 1
  for (int i = tid; i < K*C1; i += 128) {
    int k = i >> 6, c = i & 63;
    difL[k][c] = x1d[((size_t)b*N + jidx[k])*C1 + c] - xiL[c];
  }
  __syncthreads();
  const float* wr = w + (size_t)tid * (2*C1);
  #pragma unroll
  for (int k = 0; k < K; ++k) acc[k] = 0.0;
  // phase 1: diff operand, c ascending per acc
  #pragma unroll
  for (int c0 = 0; c0 < C1; c0 += 16) {
    double wd[16];
    #pragma unroll
    for (int i = 0; i < 16; ++i) wd[i] = (double)wr[c0+i];
    #pragma unroll
    for (int k = 0; k < K; ++k) {
      #pragma unroll
      for (int i = 0; i < 16; ++i) acc[k] = fma(wd[i], difL[k][c0+i], acc[k]);
    }
  }
  // phase 2: x_rep operand, c ascending per acc
  #pragma unroll
  for (int c0 = 0; c0 < C1; c0 += 16) {
    double wd[16], xiv[16];
    #pragma unroll
    for (int i = 0; i < 16; ++i) { wd[i] = (double)wr[C1+c0+i]; xiv[i] = xiL[c0+i]; }
    #pragma unroll
    for (int k = 0; k < K; ++k) {
      #pragma unroll
      for (int i = 0; i < 16; ++i) acc[k] = fma(wd[i], xiv[i], acc[k]);
    }
  }
}

// ---- conv2 pass0: conv ONCE + stats + hmax/hmin (f64) store (r15-proven) ----
__global__ __launch_bounds__(128, 1) void conv2_p0(
    const double* __restrict__ x1d, const int* __restrict__ idx,
    const float* __restrict__ w,
    double* __restrict__ sS, double* __restrict__ sQ,
    double* __restrict__ hmx2, double* __restrict__ hmn2) {
  int p = blockIdx.x;
  int tid = threadIdx.x;
  double acc[K];
  conv2_core(x1d, idx, w, p, tid, acc);
  double sum = 0., sq = 0., hmx = -INFINITY, hmn = INFINITY;
  #pragma unroll
  for (int k = 0; k < K; ++k) {
    sum += acc[k]; sq += acc[k]*acc[k];
    hmx = fmax(hmx, acc[k]); hmn = fmin(hmn, acc[k]);
  }
  hmx2[(size_t)p*C2 + tid] = hmx;
  hmn2[(size_t)p*C2 + tid] = hmn;
  int slice = p & (NSLICE - 1);
  atomicAdd(&sS[slice*C3 + tid], sum);
  atomicAdd(&sQ[slice*C3 + tid], sq);
}

// ---- conv2 pass1 (light): BN+LReLU at h extremes (monotone => exact) ----
__global__ __launch_bounds__(256) void conv2_p1_light(
    const double* __restrict__ hmx2, const double* __restrict__ hmn2,
    const double* __restrict__ mid, const float* __restrict__ gam,
    const float* __restrict__ bet,
    double* __restrict__ x2d, float* __restrict__ out448) {
  int i = blockIdx.x * 256 + threadIdx.x;   // grid = B*N*C2/256
  int p = i >> 7, o = i & 127;
  double m = mid[o], is = mid[C3 + o];
  double g = gam[o], bb = bet[o];
  double y1 = ((hmx2[i] - m) * is) * g + bb;
  y1 = y1 > 0.0 ? y1 : 0.2 * y1;
  double y2 = ((hmn2[i] - m) * is) * g + bb;
  y2 = y2 > 0.0 ? y2 : 0.2 * y2;
  double mxv = fmax(y1, y2);
  x2d[i] = mxv;
  out448[(size_t)p*448 + C1 + o] = (float)mxv;
}

// ---- conv3 pass0 v6: wave (kg,oh) covers 128 o's x its 10-k half.
// SINGLE interleaved acc[20] (first 10 = o0, last 10 = o1), chunk-16 weights,
// straight-line body. Per-(o,k) fmaf chain = r12 order (base then c asc).
// Partial extremes -> per-kg planes (exact combine); partial f64 stats ->
// atomicAdd (layer-3 value path; reorder invisible at threshold). ----
__global__ __launch_bounds__(256, 1) void conv3_p0(
    const float* __restrict__ x2f, const int* __restrict__ idx,
    const float* __restrict__ w,
    double* __restrict__ sS, double* __restrict__ sQ,
    float* __restrict__ hmx3, float* __restrict__ hmn3) {
  int p = blockIdx.x;
  int tid = threadIdx.x;
  int lane = tid & 63;
  int wv = tid >> 6;
  int kg = wv >> 1;           // 0/1: k-half
  int oh = wv & 1;            // 0/1: o-half
  int b = p >> 11;
  __shared__ float xjL[K][C2];
  __shared__ float xiL[C2];
  __shared__ int jidx[K];
  if (tid < K) jidx[tid] = idx[(size_t)p*K + tid];
  if (tid < C2) xiL[tid] = x2f[(size_t)p*C2 + tid];
  __syncthreads();
  #pragma unroll 1
  for (int i = tid; i < K*C2; i += 256) {
    int k = i >> 7, c = i & 127;
    xjL[k][c] = x2f[((size_t)b*N + jidx[k])*C2 + c];
  }
  __syncthreads();
  int o0 = lane + (oh << 7);
  int o1 = o0 + 64;
  const float* wr0 = w + (size_t)o0 * (2*C2);
  const float* wr1 = w + (size_t)o1 * (2*C2);
  float base0 = 0.f, base1 = 0.f;
  #pragma unroll
  for (int c0 = 0; c0 < C2; c0 += 16) {
    #pragma unroll
    for (int i = 0; i < 16; ++i) {
      float xv = xiL[c0+i];
      base0 = fmaf(wr0[C2+c0+i] - wr0[c0+i], xv, base0);
      base1 = fmaf(wr1[C2+c0+i] - wr1[c0+i], xv, base1);
    }
  }
  float acc[2*10];
  #pragma unroll
  for (int kk = 0; kk < 10; ++kk) { acc[kk] = base0; acc[10+kk] = base1; }
  #pragma unroll
  for (int c0 = 0; c0 < C2; c0 += 16) {
    float w0[16], w1v[16];
    #pragma unroll
    for (int i = 0; i < 16; ++i) { w0[i] = wr0[c0+i]; w1v[i] = wr1[c0+i]; }
    #pragma unroll
    for (int kk = 0; kk < 10; ++kk) {
      const float* xk = xjL[kg*10 + kk] + c0;
      #pragma unroll
      for (int i = 0; i < 16; ++i) acc[kk]    = fmaf(w0[i],  xk[i], acc[kk]);
      #pragma unroll
      for (int i = 0; i < 16; ++i) acc[10+kk] = fmaf(w1v[i], xk[i], acc[10+kk]);
    }
  }
  double s0 = 0., q0 = 0., s1 = 0., q1 = 0.;
  float m0 = -INFINITY, n0 = INFINITY, m1 = -INFINITY, n1 = INFINITY;
  #pragma unroll
  for (int kk = 0; kk < 10; ++kk) {
    double h0 = (double)acc[kk];    s0 += h0; q0 += h0*h0;
    m0 = fmaxf(m0, acc[kk]);  n0 = fminf(n0, acc[kk]);
    double h1 = (double)acc[10+kk]; s1 += h1; q1 += h1*h1;
    m1 = fmaxf(m1, acc[10+kk]); n1 = fminf(n1, acc[10+kk]);
  }
  size_t plane = (size_t)kg * B * N * C3;
  hmx3[plane + (size_t)p*C3 + o0] = m0; hmn3[plane + (size_t)p*C3 + o0] = n0;
  hmx3[plane + (size_t)p*C3 + o1] = m1; hmn3[plane + (size_t)p*C3 + o1] = n1;
  int slice = p & (NSLICE - 1);
  atomicAdd(&sS[slice*C3 + o0], s0);
  atomicAdd(&sQ[slice*C3 + o0], q0);
  atomicAdd(&sS[slice*C3 + o1], s1);
  atomicAdd(&sQ[slice*C3 + o1], q1);
}

// ---- conv3 pass1 (light): combine kg planes (exact), BN+LReLU at extremes ----
__global__ __launch_bounds__(256) void conv3_p1_light(
    const float* __restrict__ hmx3, const float* __restrict__ hmn3,
    const double* __restrict__ mid, const float* __restrict__ gam,
    const float* __restrict__ bet, float* __restrict__ out448) {
  int i = blockIdx.x * 256 + threadIdx.x;   // grid = B*N*C3/256
  int p = i >> 8, o = i & 255;
  size_t plane = (size_t)B * N * C3;
  float hmx = fmaxf(hmx3[i], hmx3[plane + i]);
  float hmn = fminf(hmn3[i], hmn3[plane + i]);
  float m = (float)mid[o], is = (float)mid[C3 + o];
  float g = gam[o], bb = bet[o];
  float y1 = (hmx - m) * is * g + bb;
  y1 = y1 > 0.f ? y1 : 0.2f * y1;
  float y2 = (hmn - m) * is * g + bb;
  y2 = y2 > 0.f ? y2 : 0.2f * y2;
  out448[(size_t)p*448 + C1 + C2 + o] = fmaxf(y1, y2);
}

// ---- finalize BN stats (f64) ----
__global__ void finalize_stats(const double* __restrict__ sS, const double* __restrict__ sQ,
                               double* __restrict__ mid, int C) {
  int o = threadIdx.x;
  if (o >= C) return;
  double s = 0., q = 0.;
  for (int i = 0; i < NSLICE; ++i) { s += sS[i*C3 + o]; q += sQ[i*C3 + o]; }
  double m = s / COUNT;
  double v = q / COUNT - m*m;
  mid[o] = m;
  mid[C3 + o] = 1.0 / sqrt(v + BNEPS);
}

} // namespace

extern "C" void kernel_launch(void* const* d_in, const int* in_sizes, int n_in,
                              void* d_out, int out_size, void* d_ws, size_t ws_size,
                              hipStream_t stream) {
  (void)in_sizes; (void)n_in; (void)out_size; (void)ws_size;
  const float* x   = (const float*)d_in[0];
  const float* nrm = (const float*)d_in[1];
  const float* w1  = (const float*)d_in[2];
  const float* g1  = (const float*)d_in[3];
  const float* b1  = (const float*)d_in[4];
  const float* w2  = (const float*)d_in[5];
  const float* g2  = (const float*)d_in[6];
  const float* b2  = (const float*)d_in[7];
  const float* w3  = (const float*)d_in[8];
  const float* g3  = (const float*)d_in[9];
  const float* b3  = (const float*)d_in[10];
  float* out = (float*)d_out;
  char*  ws  = (char*)d_ws;

  int*    idx1 = (int*)(ws + OFF_IDX1);
  int*    idx2 = (int*)(ws + OFF_IDX2);
  double* x1d  = (double*)(ws + OFF_X1D);
  double* x2d  = (double*)(ws + OFF_X2D);
  double* sS   = (double*)(ws + OFF_STATS);
  double* sQ   = sS + (size_t)NSLICE * C3;
  double* mid  = (double*)(ws + OFF_MI);
  float*  x2f  = (float*)(ws + OFF_X2F);
  float*  xx2f = (float*)(ws + OFF_XX2F);
  char*   big  = ws + OFF_BIG;
  double* hmx2 = (double*)big;                                   // conv2_p0..p1
  double* hmn2 = hmx2 + (size_t)B*N*C2;
  float*  dist = (float*)big;                                    // dist..knn_feat
  float*  hmx3 = (float*)big;                                    // conv3_p0..p1 (2 planes)
  float*  hmn3 = hmx3 + (size_t)2*B*N*C3;

  float* outR1 = out + (size_t)B * N * 448;
  float* outR2 = outR1 + (size_t)B * N * 9;

  // kNN1 — numpy-f32-faithful formula
  knn_xyz_f32<<<B*N/64, 64, 0, stream>>>(x, idx1);

  // layer 1 (f64 two-pass)
  hipMemsetAsync(sS, 0, (size_t)2*NSLICE*C3*sizeof(double), stream);
  l1_kernel<0><<<B*N, 64, 0, stream>>>(x, nrm, w1, idx1, sS, sQ, nullptr, nullptr, nullptr,
                                       nullptr, nullptr, outR1, outR2);
  finalize_stats<<<1, C3, 0, stream>>>(sS, sQ, mid, C1);
  l1_kernel<1><<<B*N, 64, 0, stream>>>(x, nrm, w1, idx1, nullptr, nullptr, mid, g1, b1,
                                       x1d, out, outR1, outR2);

  // layer 2: conv once (bit-frozen core) + extremes; light BN finish
  hipMemsetAsync(sS, 0, (size_t)2*NSLICE*C3*sizeof(double), stream);
  conv2_p0<<<B*N, 128, 0, stream>>>(x1d, idx1, w2, sS, sQ, hmx2, hmn2);
  finalize_stats<<<1, C3, 0, stream>>>(sS, sQ, mid, C2);
  conv2_p1_light<<<B*N*C2/256, 256, 0, stream>>>(hmx2, hmn2, mid, g2, b2, x2d, out);

  // kNN2 — numpy-f32-faithful, all batches fused; wave-parallel coalesced top-k
  xx2f_kernel<<<B*N/64, 64, 0, stream>>>(x2d, x2f, xx2f);
  dist_f32_kernel<<<dim3(N/64, N/64, B), 256, 0, stream>>>(x2f, xx2f, dist);
  knn_feat_wave<<<B*N/4, 256, 0, stream>>>(dist, idx2);

  // layer 3: conv once (wave-split, plane extremes) + light BN finish
  hipMemsetAsync(sS, 0, (size_t)2*NSLICE*C3*sizeof(double), stream);
  conv3_p0<<<B*N, 256, 0, stream>>>(x2f, idx2, w3, sS, sQ, hmx3, hmn3);
  finalize_stats<<<1, C3, 0, stream>>>(sS, sQ, mid, C3);
  conv3_p1_light<<<B*N*C3/256, 256, 0, stream>>>(hmx3, hmn3, mid, g3, b3, out);
}

// Round 18
// 1958.417 us; speedup vs baseline: 2.2573x; 1.5863x over previous
//
#include <hip/hip_runtime.h>
#include <hip/hip_bf16.h>
#include <math.h>

namespace {

constexpr int B  = 8;
constexpr int N  = 2048;     // power of two: n = p & 2047, b = p >> 11
constexpr int K  = 20;
constexpr int C1 = 64, C2 = 128, C3 = 256;
constexpr int NSLICE = 64;
constexpr double COUNT = 327680.0;   // B*N*K
constexpr double BNEPS = 1e-5;

// ---- workspace layout (bytes) ----
constexpr size_t OFF_IDX1  = 0;                                  // B*N*K int
constexpr size_t OFF_IDX2  = OFF_IDX1 + (size_t)B*N*K*4;         // B*N*K int
constexpr size_t OFF_X1D   = OFF_IDX2 + (size_t)B*N*K*4;         // B*N*C1 f64
constexpr size_t OFF_X2D   = OFF_X1D  + (size_t)B*N*C1*8;        // B*N*C2 f64
constexpr size_t OFF_STATS = OFF_X2D  + (size_t)B*N*C2*8;        // 2*NSLICE*C3 f64
constexpr size_t OFF_MI    = OFF_STATS+ (size_t)2*NSLICE*C3*8;   // 2*C3 f64
constexpr size_t OFF_X2F   = OFF_MI   + 4096;                    // B*N*C2 f32
constexpr size_t OFF_XX2F  = OFF_X2F  + (size_t)B*N*C2*4;        // B*N f32
constexpr size_t OFF_BIG   = OFF_XX2F + (size_t)B*N*4;           // shared big region
// big region, sequential lifetimes (within proven footprint):
//   {hmax2,hmin2 f64} -> dist f32 (134.2 MB) -> {hmax3,hmin3 f32}

// ---- strict-rounding f32 helpers (block FMA contraction / reassociation) ----
__device__ __forceinline__ float fmul32(float a, float b){ return __fmul_rn(a,b); }
__device__ __forceinline__ float fadd32(float a, float b){ return __fadd_rn(a,b); }
__device__ __forceinline__ float fsub32(float a, float b){ return __fsub_rn(a,b); }

// ---- per-thread insertion top-20 on f32 (largest, ties keep lowest index) ----
__device__ __forceinline__ void insert_candidatef(float v, int j,
                                                  float (&best)[K], int (&bidx)[K]) {
  if (v > best[K-1]) {
    best[K-1] = v; bidx[K-1] = j;
    #pragma unroll
    for (int i = K-1; i >= 1; --i) {
      if (best[i] > best[i-1]) {
        float tv = best[i]; best[i] = best[i-1]; best[i-1] = tv;
        int   ti = bidx[i]; bidx[i] = bidx[i-1]; bidx[i-1] = ti;
      }
    }
  }
}

// ---- kNN on 3-D coords, numpy-f32-faithful (BIT-FROZEN) ----
__global__ __launch_bounds__(64) void knn_xyz_f32(const float* __restrict__ x,
                                                  int* __restrict__ idxo) {
  int row = blockIdx.x * 64 + threadIdx.x;   // grid = B*N/64
  int b = row >> 11, n = row & (N - 1);
  const float* xb = x + (size_t)b * N * 3;
  float xi0 = xb[(size_t)n*3], xi1 = xb[(size_t)n*3+1], xi2 = xb[(size_t)n*3+2];
  float xxi = fadd32(fadd32(fmul32(xi0,xi0), fmul32(xi1,xi1)), fmul32(xi2,xi2));
  float best[K]; int bidx[K];
  #pragma unroll
  for (int i = 0; i < K; ++i) { best[i] = -INFINITY; bidx[i] = 0; }
  for (int j = 0; j < N; ++j) {
    float a = xb[(size_t)j*3], c = xb[(size_t)j*3+1], d = xb[(size_t)j*3+2];
    float xxj   = fadd32(fadd32(fmul32(a,a), fmul32(c,c)), fmul32(d,d));
    float inner = fadd32(fadd32(fmul32(xi0,a), fmul32(xi1,c)), fmul32(xi2,d));
    float v = fsub32(fsub32(fmul32(2.f, inner), xxi), xxj);
    insert_candidatef(v, j, best, bidx);
  }
  int* o = idxo + (size_t)row * K;
  #pragma unroll
  for (int i = 0; i < K; ++i) o[i] = bidx[i];
}

// ---- x2 -> f32 copy + numpy pairwise(n=128) sum of squares (BIT-FROZEN) ----
__global__ __launch_bounds__(64) void xx2f_kernel(const double* __restrict__ x2d,
                                                  float* __restrict__ x2f,
                                                  float* __restrict__ xx2f) {
  int row = blockIdx.x * 64 + threadIdx.x;   // grid = B*N/64
  const double* src = x2d + (size_t)row * C2;
  float* dst = x2f + (size_t)row * C2;
  float sq[C2];
  #pragma unroll 8
  for (int c = 0; c < C2; ++c) {
    float v = (float)src[c];
    dst[c] = v;
    sq[c] = fmul32(v, v);
  }
  float r0=sq[0], r1=sq[1], r2=sq[2], r3=sq[3], r4=sq[4], r5=sq[5], r6=sq[6], r7=sq[7];
  #pragma unroll
  for (int i = 8; i < 128; i += 8) {
    r0 = fadd32(r0, sq[i+0]); r1 = fadd32(r1, sq[i+1]);
    r2 = fadd32(r2, sq[i+2]); r3 = fadd32(r3, sq[i+3]);
    r4 = fadd32(r4, sq[i+4]); r5 = fadd32(r5, sq[i+5]);
    r6 = fadd32(r6, sq[i+6]); r7 = fadd32(r7, sq[i+7]);
  }
  xx2f[row] = fadd32(fadd32(fadd32(r0,r1), fadd32(r2,r3)),
                     fadd32(fadd32(r4,r5), fadd32(r6,r7)));
}

// ---- all-batch neg-distance matrix, f32 sequential (BIT-FROZEN inner) ----
__global__ __launch_bounds__(256) void dist_f32_kernel(const float* __restrict__ x2f,
                                                       const float* __restrict__ xx2f,
                                                       float* __restrict__ dist) {
  int bz = blockIdx.z;
  const float* x2b  = x2f  + (size_t)bz * N * C2;
  const float* xx2b = xx2f + (size_t)bz * N;
  float* db = dist + (size_t)bz * N * N;
  int ti = blockIdx.y * 64;
  int tj = blockIdx.x * 64;
  int tid = threadIdx.x;
  int tr = tid >> 4, tc = tid & 15;
  __shared__ float A[64][9], Bm[64][9];
  float acc[4][4];
  #pragma unroll
  for (int u = 0; u < 4; ++u)
    #pragma unroll
    for (int v = 0; v < 4; ++v) acc[u][v] = 0.f;
  for (int c0 = 0; c0 < C2; c0 += 8) {
    for (int i = tid; i < 512; i += 256) {
      int r = i >> 3, c = i & 7;
      A[r][c]  = x2b[(size_t)(ti + r)*C2 + c0 + c];
      Bm[r][c] = x2b[(size_t)(tj + r)*C2 + c0 + c];
    }
    __syncthreads();
    #pragma unroll
    for (int c = 0; c < 8; ++c) {       // ascending c: exact sequential order
      float a[4], bv[4];
      #pragma unroll
      for (int u = 0; u < 4; ++u) a[u] = A[tr*4 + u][c];
      #pragma unroll
      for (int v = 0; v < 4; ++v) bv[v] = Bm[tc*4 + v][c];
      #pragma unroll
      for (int u = 0; u < 4; ++u)
        #pragma unroll
        for (int v = 0; v < 4; ++v)
          acc[u][v] = fadd32(acc[u][v], fmul32(a[u], bv[v]));
    }
    __syncthreads();
  }
  #pragma unroll
  for (int u = 0; u < 4; ++u) {
    int i = ti + tr*4 + u;
    float xxi = xx2b[i];
    #pragma unroll
    for (int v = 0; v < 4; ++v) {
      int j = tj + tc*4 + v;
      db[(size_t)i*N + j] = fsub32(fsub32(fmul32(2.f, acc[u][v]), xxi), xx2b[j]);
    }
  }
}

// ---- wave-parallel top-20 on frozen dist values (coalesced reads) ----
__global__ __launch_bounds__(256) void knn_feat_wave(const float* __restrict__ dist,
                                                     int* __restrict__ idxo) {
  int row  = blockIdx.x * 4 + (threadIdx.x >> 6);   // grid = B*N/4
  int lane = threadIdx.x & 63;
  const float* dr = dist + (size_t)row * N;
  float vals[32];
  #pragma unroll
  for (int t = 0; t < 32; ++t) vals[t] = dr[lane + (t << 6)];   // coalesced
  int* out = idxo + (size_t)row * K;
  for (int sel = 0; sel < K; ++sel) {
    float best = -INFINITY; int bt = 0;
    #pragma unroll
    for (int t = 0; t < 32; ++t)
      if (vals[t] > best) { best = vals[t]; bt = t; }
    int bcol = lane + (bt << 6);
    #pragma unroll
    for (int off = 32; off >= 1; off >>= 1) {
      float ov = __shfl_xor(best, off, 64);
      int   oc = __shfl_xor(bcol, off, 64);
      if (ov > best || (ov == best && oc < bcol)) { best = ov; bcol = oc; }
    }
    if (lane == 0) out[sel] = bcol;
    int kill = ((bcol & 63) == lane) ? (bcol >> 6) : 32;
    #pragma unroll
    for (int t = 0; t < 32; ++t) if (t == kill) vals[t] = -INFINITY;
  }
}

// ---- layer 1 (two-pass, f64): geometry + conv1 (BIT-FROZEN) ----
template<int PASS>
__global__ __launch_bounds__(64) void l1_kernel(
    const float* __restrict__ x, const float* __restrict__ nrm,
    const float* __restrict__ w1, const int* __restrict__ idx1,
    double* __restrict__ sS, double* __restrict__ sQ,
    const double* __restrict__ mid, const float* __restrict__ g1, const float* __restrict__ b1,
    double* __restrict__ x1d, float* __restrict__ out448,
    float* __restrict__ outR1, float* __restrict__ outR2) {
  int p = blockIdx.x;
  int tid = threadIdx.x;
  int b = p >> 11, n = p & (N - 1);
  __shared__ float  wl[C1 * 9];
  __shared__ double rotd[K][3];
  __shared__ double fld[K][9];
  for (int i = tid; i < C1 * 9; i += 64) wl[i] = w1[i];
  const float* xb = x + (size_t)b * N * 3;
  double nx = nrm[(size_t)p*3], ny = nrm[(size_t)p*3+1], nz = nrm[(size_t)p*3+2];
  double vx = ny, vy = -nx;
  double s = 1.0 / fmax(1.0 + nz, 1e-8);
  double vxy = vx * vy;
  double R1v[9];
  R1v[0] = 1.0 - s*(vy*vy); R1v[1] = s*vxy;           R1v[2] = vy;
  R1v[3] = s*vxy;           R1v[4] = 1.0 - s*(vx*vx); R1v[5] = -vx;
  R1v[6] = -vy;             R1v[7] = vx;              R1v[8] = 1.0 - s*(vx*vx + vy*vy);
  double xi0 = xb[(size_t)n*3], xi1 = xb[(size_t)n*3+1], xi2 = xb[(size_t)n*3+2];
  if (tid < K) {
    int j = idx1[(size_t)p*K + tid];
    double d0 = (double)xb[(size_t)j*3]   - xi0;
    double d1 = (double)xb[(size_t)j*3+1] - xi1;
    double d2 = (double)xb[(size_t)j*3+2] - xi2;
    rotd[tid][0] = R1v[0]*d0 + R1v[1]*d1 + R1v[2]*d2;
    rotd[tid][1] = R1v[3]*d0 + R1v[4]*d1 + R1v[5]*d2;
    rotd[tid][2] = R1v[6]*d0 + R1v[7]*d1 + R1v[8]*d2;
  }
  __syncthreads();
  double mx = 0.0, my = 0.0;
  #pragma unroll
  for (int k = 0; k < K; ++k) { mx += rotd[k][0]; my += rotd[k][1]; }
  mx /= 20.0; my /= 20.0;
  double r = sqrt(mx*mx + my*my);
  double ct = 1.0, st = 0.0;
  if (r > 0.0) { ct = mx / r; st = my / r; }   // cos/sin of atan2(my,mx)
  if (tid < K) {
    double r0 = rotd[tid][0], r1 = rotd[tid][1], r2 = rotd[tid][2];
    double a0 = ct*r0 + st*r1;
    double a1 = ct*r1 - st*r0;
    fld[tid][0] = a0;  fld[tid][1] = a1;   fld[tid][2] = r2;
    fld[tid][3] = a0;  fld[tid][4] = -a1;  fld[tid][5] = r2;   // xz-mirror
    fld[tid][6] = xi0; fld[tid][7] = xi1;  fld[tid][8] = xi2;  // x_rep
  }
  if (PASS == 0 && tid == 0) {
    float* o1 = outR1 + (size_t)p * 9;
    #pragma unroll
    for (int i = 0; i < 9; ++i) o1[i] = (float)R1v[i];
    float* o2 = outR2 + (size_t)p * 9;
    o2[0] = (float)ct;  o2[1] = (float)st; o2[2] = 0.f;
    o2[3] = (float)-st; o2[4] = (float)ct; o2[5] = 0.f;
    o2[6] = 0.f;        o2[7] = 0.f;       o2[8] = 1.f;
  }
  __syncthreads();
  int o = tid;
  if (PASS == 0) {
    double sum = 0., sq = 0.;
    #pragma unroll
    for (int k = 0; k < K; ++k) {
      double h = 0.;
      #pragma unroll
      for (int c = 0; c < 9; ++c) h = fma((double)wl[o*9 + c], fld[k][c], h);
      sum += h; sq += h*h;
    }
    int slice = p & (NSLICE - 1);
    atomicAdd(&sS[slice*C3 + o], sum);
    atomicAdd(&sQ[slice*C3 + o], sq);
  } else {
    double m = mid[o], is = mid[C3 + o];
    double g = g1[o], bb = b1[o];
    double mxv = -INFINITY;
    #pragma unroll
    for (int k = 0; k < K; ++k) {
      double h = 0.;
      #pragma unroll
      for (int c = 0; c < 9; ++c) h = fma((double)wl[o*9 + c], fld[k][c], h);
      double y = ((h - m) * is) * g + bb;
      y = y > 0.0 ? y : 0.2 * y;
      mxv = fmax(mxv, y);
    }
    x1d[(size_t)p*C1 + o] = mxv;
    out448[(size_t)p*448 + o] = (float)mxv;
  }
}

// ---- conv2 core: r12-proven LDS op sequence, 128 threads (BIT-FROZEN) ----
__device__ __forceinline__ void conv2_core(const double* __restrict__ x1d,
                                           const int* __restrict__ idx,
                                           const float* __restrict__ w,
                                           int p, int tid, double (&acc)[K]) {
  int b = p >> 11;
  __shared__ double difL[K][C1];
  __shared__ double xiL[C1];
  __shared__ int jidx[K];
  if (tid < K) jidx[tid] = idx[(size_t)p*K + tid];
  if (tid < C1) xiL[tid] = x1d[(size_t)p*C1 + tid];
  __syncthreads();
  #pragma unroll 1
  for (int i = tid; i < K*C1; i += 128) {
    int k = i >> 6, c = i & 63;
    difL[k][c] = x1d[((size_t)b*N + jidx[k])*C1 + c] - xiL[c];
  }
  __syncthreads();
  const float* wr = w + (size_t)tid * (2*C1);
  #pragma unroll
  for (int k = 0; k < K; ++k) acc[k] = 0.0;
  // phase 1: diff operand, c ascending per acc
  #pragma unroll
  for (int c0 = 0; c0 < C1; c0 += 16) {
    double wd[16];
    #pragma unroll
    for (int i = 0; i < 16; ++i) wd[i] = (double)wr[c0+i];
    #pragma unroll
    for (int k = 0; k < K; ++k) {
      #pragma unroll
      for (int i = 0; i < 16; ++i) acc[k] = fma(wd[i], difL[k][c0+i], acc[k]);
    }
  }
  // phase 2: x_rep operand, c ascending per acc
  #pragma unroll
  for (int c0 = 0; c0 < C1; c0 += 16) {
    double wd[16], xiv[16];
    #pragma unroll
    for (int i = 0; i < 16; ++i) { wd[i] = (double)wr[C1+c0+i]; xiv[i] = xiL[c0+i]; }
    #pragma unroll
    for (int k = 0; k < K; ++k) {
      #pragma unroll
      for (int i = 0; i < 16; ++i) acc[k] = fma(wd[i], xiv[i], acc[k]);
    }
  }
}

// ---- conv2 pass0: conv ONCE + stats + hmax/hmin (f64) store (r15-proven) ----
__global__ __launch_bounds__(128, 1) void conv2_p0(
    const double* __restrict__ x1d, const int* __restrict__ idx,
    const float* __restrict__ w,
    double* __restrict__ sS, double* __restrict__ sQ,
    double* __restrict__ hmx2, double* __restrict__ hmn2) {
  int p = blockIdx.x;
  int tid = threadIdx.x;
  double acc[K];
  conv2_core(x1d, idx, w, p, tid, acc);
  double sum = 0., sq = 0., hmx = -INFINITY, hmn = INFINITY;
  #pragma unroll
  for (int k = 0; k < K; ++k) {
    sum += acc[k]; sq += acc[k]*acc[k];
    hmx = fmax(hmx, acc[k]); hmn = fmin(hmn, acc[k]);
  }
  hmx2[(size_t)p*C2 + tid] = hmx;
  hmn2[(size_t)p*C2 + tid] = hmn;
  int slice = p & (NSLICE - 1);
  atomicAdd(&sS[slice*C3 + tid], sum);
  atomicAdd(&sQ[slice*C3 + tid], sq);
}

// ---- conv2 pass1 (light): BN+LReLU at h extremes (monotone => exact) ----
__global__ __launch_bounds__(256) void conv2_p1_light(
    const double* __restrict__ hmx2, const double* __restrict__ hmn2,
    const double* __restrict__ mid, const float* __restrict__ gam,
    const float* __restrict__ bet,
    double* __restrict__ x2d, float* __restrict__ out448) {
  int i = blockIdx.x * 256 + threadIdx.x;   // grid = B*N*C2/256
  int p = i >> 7, o = i & 127;
  double m = mid[o], is = mid[C3 + o];
  double g = gam[o], bb = bet[o];
  double y1 = ((hmx2[i] - m) * is) * g + bb;
  y1 = y1 > 0.0 ? y1 : 0.2 * y1;
  double y2 = ((hmn2[i] - m) * is) * g + bb;
  y2 = y2 > 0.0 ? y2 : 0.2 * y2;
  double mxv = fmax(y1, y2);
  x2d[i] = mxv;
  out448[(size_t)p*448 + C1 + o] = (float)mxv;
}

// ---- conv3 pass0: r12-proven skeleton (256 thr, acc[K], VGPR~80) — conv
// ONCE + stats + f32 hmax/hmin store (no h3 buffer at all). ----
__global__ __launch_bounds__(256, 1) void conv3_p0(
    const float* __restrict__ x2f, const int* __restrict__ idx,
    const float* __restrict__ w,
    double* __restrict__ sS, double* __restrict__ sQ,
    float* __restrict__ hmx3, float* __restrict__ hmn3) {
  int p = blockIdx.x;
  int tid = threadIdx.x;
  int b = p >> 11;
  __shared__ float xjL[K][C2];
  __shared__ float xiL[C2];
  __shared__ int jidx[K];
  if (tid < K) jidx[tid] = idx[(size_t)p*K + tid];
  if (tid < C2) xiL[tid] = x2f[(size_t)p*C2 + tid];
  __syncthreads();
  #pragma unroll 1
  for (int i = tid; i < K*C2; i += 256) {
    int k = i >> 7, c = i & 127;
    xjL[k][c] = x2f[((size_t)b*N + jidx[k])*C2 + c];
  }
  __syncthreads();
  const float* wr = w + (size_t)tid * (2*C2);
  float base = 0.f;
  #pragma unroll
  for (int c0 = 0; c0 < C2; c0 += 32) {
    #pragma unroll
    for (int i = 0; i < 32; ++i)
      base = fmaf(wr[C2+c0+i] - wr[c0+i], xiL[c0+i], base);
  }
  float acc[K];
  #pragma unroll
  for (int k = 0; k < K; ++k) acc[k] = base;
  #pragma unroll
  for (int c0 = 0; c0 < C2; c0 += 32) {
    float wd[32];
    #pragma unroll
    for (int i = 0; i < 32; ++i) wd[i] = wr[c0+i];
    #pragma unroll
    for (int k = 0; k < K; ++k) {
      #pragma unroll
      for (int i = 0; i < 32; ++i) acc[k] = fmaf(wd[i], xjL[k][c0+i], acc[k]);
    }
  }
  double sum = 0., sq = 0.;
  float hmx = -INFINITY, hmn = INFINITY;
  #pragma unroll
  for (int k = 0; k < K; ++k) {
    double h = (double)acc[k];
    sum += h; sq += h*h;
    hmx = fmaxf(hmx, acc[k]); hmn = fminf(hmn, acc[k]);
  }
  hmx3[(size_t)p*C3 + tid] = hmx;
  hmn3[(size_t)p*C3 + tid] = hmn;
  int slice = p & (NSLICE - 1);
  atomicAdd(&sS[slice*C3 + tid], sum);
  atomicAdd(&sQ[slice*C3 + tid], sq);
}

// ---- conv3 pass1 (light): BN+LReLU at extremes, fmax -> out ----
__global__ __launch_bounds__(256) void conv3_p1_light(
    const float* __restrict__ hmx3, const float* __restrict__ hmn3,
    const double* __restrict__ mid, const float* __restrict__ gam,
    const float* __restrict__ bet, float* __restrict__ out448) {
  int i = blockIdx.x * 256 + threadIdx.x;   // grid = B*N*C3/256
  int p = i >> 8, o = i & 255;
  float m = (float)mid[o], is = (float)mid[C3 + o];
  float g = gam[o], bb = bet[o];
  float y1 = (hmx3[i] - m) * is * g + bb;
  y1 = y1 > 0.f ? y1 : 0.2f * y1;
  float y2 = (hmn3[i] - m) * is * g + bb;
  y2 = y2 > 0.f ? y2 : 0.2f * y2;
  out448[(size_t)p*448 + C1 + C2 + o] = fmaxf(y1, y2);
}

// ---- finalize BN stats (f64) ----
__global__ void finalize_stats(const double* __restrict__ sS, const double* __restrict__ sQ,
                               double* __restrict__ mid, int C) {
  int o = threadIdx.x;
  if (o >= C) return;
  double s = 0., q = 0.;
  for (int i = 0; i < NSLICE; ++i) { s += sS[i*C3 + o]; q += sQ[i*C3 + o]; }
  double m = s / COUNT;
  double v = q / COUNT - m*m;
  mid[o] = m;
  mid[C3 + o] = 1.0 / sqrt(v + BNEPS);
}

} // namespace

extern "C" void kernel_launch(void* const* d_in, const int* in_sizes, int n_in,
                              void* d_out, int out_size, void* d_ws, size_t ws_size,
                              hipStream_t stream) {
  (void)in_sizes; (void)n_in; (void)out_size; (void)ws_size;
  const float* x   = (const float*)d_in[0];
  const float* nrm = (const float*)d_in[1];
  const float* w1  = (const float*)d_in[2];
  const float* g1  = (const float*)d_in[3];
  const float* b1  = (const float*)d_in[4];
  const float* w2  = (const float*)d_in[5];
  const float* g2  = (const float*)d_in[6];
  const float* b2  = (const float*)d_in[7];
  const float* w3  = (const float*)d_in[8];
  const float* g3  = (const float*)d_in[9];
  const float* b3  = (const float*)d_in[10];
  float* out = (float*)d_out;
  char*  ws  = (char*)d_ws;

  int*    idx1 = (int*)(ws + OFF_IDX1);
  int*    idx2 = (int*)(ws + OFF_IDX2);
  double* x1d  = (double*)(ws + OFF_X1D);
  double* x2d  = (double*)(ws + OFF_X2D);
  double* sS   = (double*)(ws + OFF_STATS);
  double* sQ   = sS + (size_t)NSLICE * C3;
  double* mid  = (double*)(ws + OFF_MI);
  float*  x2f  = (float*)(ws + OFF_X2F);
  float*  xx2f = (float*)(ws + OFF_XX2F);
  char*   big  = ws + OFF_BIG;
  double* hmx2 = (double*)big;                                   // conv2_p0..p1
  double* hmn2 = hmx2 + (size_t)B*N*C2;
  float*  dist = (float*)big;                                    // dist..knn_feat
  float*  hmx3 = (float*)big;                                    // conv3_p0..p1
  float*  hmn3 = hmx3 + (size_t)B*N*C3;

  float* outR1 = out + (size_t)B * N * 448;
  float* outR2 = outR1 + (size_t)B * N * 9;

  // kNN1 — numpy-f32-faithful formula
  knn_xyz_f32<<<B*N/64, 64, 0, stream>>>(x, idx1);

  // layer 1 (f64 two-pass)
  hipMemsetAsync(sS, 0, (size_t)2*NSLICE*C3*sizeof(double), stream);
  l1_kernel<0><<<B*N, 64, 0, stream>>>(x, nrm, w1, idx1, sS, sQ, nullptr, nullptr, nullptr,
                                       nullptr, nullptr, outR1, outR2);
  finalize_stats<<<1, C3, 0, stream>>>(sS, sQ, mid, C1);
  l1_kernel<1><<<B*N, 64, 0, stream>>>(x, nrm, w1, idx1, nullptr, nullptr, mid, g1, b1,
                                       x1d, out, outR1, outR2);

  // layer 2: conv once (bit-frozen core) + extremes; light BN finish
  hipMemsetAsync(sS, 0, (size_t)2*NSLICE*C3*sizeof(double), stream);
  conv2_p0<<<B*N, 128, 0, stream>>>(x1d, idx1, w2, sS, sQ, hmx2, hmn2);
  finalize_stats<<<1, C3, 0, stream>>>(sS, sQ, mid, C2);
  conv2_p1_light<<<B*N*C2/256, 256, 0, stream>>>(hmx2, hmn2, mid, g2, b2, x2d, out);

  // kNN2 — numpy-f32-faithful, all batches fused; wave-parallel coalesced top-k
  xx2f_kernel<<<B*N/64, 64, 0, stream>>>(x2d, x2f, xx2f);
  dist_f32_kernel<<<dim3(N/64, N/64, B), 256, 0, stream>>>(x2f, xx2f, dist);
  knn_feat_wave<<<B*N/4, 256, 0, stream>>>(dist, idx2);

  // layer 3: conv once (f32, r12 skeleton) + extremes; light BN finish
  hipMemsetAsync(sS, 0, (size_t)2*NSLICE*C3*sizeof(double), stream);
  conv3_p0<<<B*N, 256, 0, stream>>>(x2f, idx2, w3, sS, sQ, hmx3, hmn3);
  finalize_stats<<<1, C3, 0, stream>>>(sS, sQ, mid, C3);
  conv3_p1_light<<<B*N*C3/256, 256, 0, stream>>>(hmx3, hmn3, mid, g3, b3, out);
}

// Round 19
// 1449.546 us; speedup vs baseline: 3.0497x; 1.3511x over previous
//
#include <hip/hip_runtime.h>
#include <hip/hip_bf16.h>
#include <math.h>

namespace {

constexpr int B  = 8;
constexpr int N  = 2048;     // power of two: n = p & 2047, b = p >> 11
constexpr int K  = 20;
constexpr int C1 = 64, C2 = 128, C3 = 256;
constexpr int NSLICE = 64;
constexpr double COUNT = 327680.0;   // B*N*K
constexpr double BNEPS = 1e-5;

// ---- workspace layout (bytes) ----
constexpr size_t OFF_IDX1  = 0;                                  // B*N*K int
constexpr size_t OFF_IDX2  = OFF_IDX1 + (size_t)B*N*K*4;         // B*N*K int
constexpr size_t OFF_X1D   = OFF_IDX2 + (size_t)B*N*K*4;         // B*N*C1 f64
constexpr size_t OFF_X2D   = OFF_X1D  + (size_t)B*N*C1*8;        // B*N*C2 f64
constexpr size_t OFF_STATS = OFF_X2D  + (size_t)B*N*C2*8;        // 2*NSLICE*C3 f64
constexpr size_t OFF_MI    = OFF_STATS+ (size_t)2*NSLICE*C3*8;   // 2*C3 f64
constexpr size_t OFF_X2F   = OFF_MI   + 4096;                    // B*N*C2 f32
constexpr size_t OFF_XX2F  = OFF_X2F  + (size_t)B*N*C2*4;        // B*N f32
constexpr size_t OFF_BIG   = OFF_XX2F + (size_t)B*N*4;           // shared big region
// big region, sequential lifetimes (within proven footprint):
//   {hmax1,hmin1 f64: 2x8.4MB} -> {hmax2,hmin2 f64: 2x16.8MB}
//   -> dist f32 (134.2 MB) -> {hmax3,hmin3 f32: 2x16.8MB}

// ---- strict-rounding f32 helpers (block FMA contraction / reassociation) ----
__device__ __forceinline__ float fmul32(float a, float b){ return __fmul_rn(a,b); }
__device__ __forceinline__ float fadd32(float a, float b){ return __fadd_rn(a,b); }
__device__ __forceinline__ float fsub32(float a, float b){ return __fsub_rn(a,b); }

// ---- kNN on 3-D coords, numpy-f32-faithful values, wave-parallel top-20.
// Per-j value = BIT-FROZEN per-element formula; butterfly comparator (desc,
// ties -> smaller index) selects identically to insertion (r11-proven). ----
__global__ __launch_bounds__(256) void knn_xyz_wave(const float* __restrict__ x,
                                                    int* __restrict__ idxo) {
  int row  = blockIdx.x * 4 + (threadIdx.x >> 6);   // grid = B*N/4
  int lane = threadIdx.x & 63;
  int b = row >> 11, n = row & (N - 1);
  const float* xb = x + (size_t)b * N * 3;
  float xi0 = xb[(size_t)n*3], xi1 = xb[(size_t)n*3+1], xi2 = xb[(size_t)n*3+2];
  float xxi = fadd32(fadd32(fmul32(xi0,xi0), fmul32(xi1,xi1)), fmul32(xi2,xi2));
  float vals[32];
  #pragma unroll
  for (int t = 0; t < 32; ++t) {
    int j = lane + (t << 6);
    float a = xb[(size_t)j*3], c = xb[(size_t)j*3+1], d = xb[(size_t)j*3+2];
    float xxj   = fadd32(fadd32(fmul32(a,a), fmul32(c,c)), fmul32(d,d));
    float inner = fadd32(fadd32(fmul32(xi0,a), fmul32(xi1,c)), fmul32(xi2,d));
    vals[t] = fsub32(fsub32(fmul32(2.f, inner), xxi), xxj);
  }
  int* out = idxo + (size_t)row * K;
  for (int sel = 0; sel < K; ++sel) {
    float best = -INFINITY; int bt = 0;
    #pragma unroll
    for (int t = 0; t < 32; ++t)
      if (vals[t] > best) { best = vals[t]; bt = t; }
    int bcol = lane + (bt << 6);
    #pragma unroll
    for (int off = 32; off >= 1; off >>= 1) {
      float ov = __shfl_xor(best, off, 64);
      int   oc = __shfl_xor(bcol, off, 64);
      if (ov > best || (ov == best && oc < bcol)) { best = ov; bcol = oc; }
    }
    if (lane == 0) out[sel] = bcol;
    int kill = ((bcol & 63) == lane) ? (bcol >> 6) : 32;
    #pragma unroll
    for (int t = 0; t < 32; ++t) if (t == kill) vals[t] = -INFINITY;
  }
}

// ---- x2 -> f32 copy + numpy pairwise(n=128) sum of squares (BIT-FROZEN) ----
__global__ __launch_bounds__(64) void xx2f_kernel(const double* __restrict__ x2d,
                                                  float* __restrict__ x2f,
                                                  float* __restrict__ xx2f) {
  int row = blockIdx.x * 64 + threadIdx.x;   // grid = B*N/64
  const double* src = x2d + (size_t)row * C2;
  float* dst = x2f + (size_t)row * C2;
  float sq[C2];
  #pragma unroll 8
  for (int c = 0; c < C2; ++c) {
    float v = (float)src[c];
    dst[c] = v;
    sq[c] = fmul32(v, v);
  }
  float r0=sq[0], r1=sq[1], r2=sq[2], r3=sq[3], r4=sq[4], r5=sq[5], r6=sq[6], r7=sq[7];
  #pragma unroll
  for (int i = 8; i < 128; i += 8) {
    r0 = fadd32(r0, sq[i+0]); r1 = fadd32(r1, sq[i+1]);
    r2 = fadd32(r2, sq[i+2]); r3 = fadd32(r3, sq[i+3]);
    r4 = fadd32(r4, sq[i+4]); r5 = fadd32(r5, sq[i+5]);
    r6 = fadd32(r6, sq[i+6]); r7 = fadd32(r7, sq[i+7]);
  }
  xx2f[row] = fadd32(fadd32(fadd32(r0,r1), fadd32(r2,r3)),
                     fadd32(fadd32(r4,r5), fadd32(r6,r7)));
}

// ---- all-batch neg-distance matrix, f32 sequential (BIT-FROZEN inner) ----
__global__ __launch_bounds__(256) void dist_f32_kernel(const float* __restrict__ x2f,
                                                       const float* __restrict__ xx2f,
                                                       float* __restrict__ dist) {
  int bz = blockIdx.z;
  const float* x2b  = x2f  + (size_t)bz * N * C2;
  const float* xx2b = xx2f + (size_t)bz * N;
  float* db = dist + (size_t)bz * N * N;
  int ti = blockIdx.y * 64;
  int tj = blockIdx.x * 64;
  int tid = threadIdx.x;
  int tr = tid >> 4, tc = tid & 15;
  __shared__ float A[64][9], Bm[64][9];
  float acc[4][4];
  #pragma unroll
  for (int u = 0; u < 4; ++u)
    #pragma unroll
    for (int v = 0; v < 4; ++v) acc[u][v] = 0.f;
  for (int c0 = 0; c0 < C2; c0 += 8) {
    for (int i = tid; i < 512; i += 256) {
      int r = i >> 3, c = i & 7;
      A[r][c]  = x2b[(size_t)(ti + r)*C2 + c0 + c];
      Bm[r][c] = x2b[(size_t)(tj + r)*C2 + c0 + c];
    }
    __syncthreads();
    #pragma unroll
    for (int c = 0; c < 8; ++c) {       // ascending c: exact sequential order
      float a[4], bv[4];
      #pragma unroll
      for (int u = 0; u < 4; ++u) a[u] = A[tr*4 + u][c];
      #pragma unroll
      for (int v = 0; v < 4; ++v) bv[v] = Bm[tc*4 + v][c];
      #pragma unroll
      for (int u = 0; u < 4; ++u)
        #pragma unroll
        for (int v = 0; v < 4; ++v)
          acc[u][v] = fadd32(acc[u][v], fmul32(a[u], bv[v]));
    }
    __syncthreads();
  }
  #pragma unroll
  for (int u = 0; u < 4; ++u) {
    int i = ti + tr*4 + u;
    float xxi = xx2b[i];
    #pragma unroll
    for (int v = 0; v < 4; ++v) {
      int j = tj + tc*4 + v;
      db[(size_t)i*N + j] = fsub32(fsub32(fmul32(2.f, acc[u][v]), xxi), xx2b[j]);
    }
  }
}

// ---- wave-parallel top-20 on frozen dist values (coalesced reads) ----
__global__ __launch_bounds__(256) void knn_feat_wave(const float* __restrict__ dist,
                                                     int* __restrict__ idxo) {
  int row  = blockIdx.x * 4 + (threadIdx.x >> 6);   // grid = B*N/4
  int lane = threadIdx.x & 63;
  const float* dr = dist + (size_t)row * N;
  float vals[32];
  #pragma unroll
  for (int t = 0; t < 32; ++t) vals[t] = dr[lane + (t << 6)];   // coalesced
  int* out = idxo + (size_t)row * K;
  for (int sel = 0; sel < K; ++sel) {
    float best = -INFINITY; int bt = 0;
    #pragma unroll
    for (int t = 0; t < 32; ++t)
      if (vals[t] > best) { best = vals[t]; bt = t; }
    int bcol = lane + (bt << 6);
    #pragma unroll
    for (int off = 32; off >= 1; off >>= 1) {
      float ov = __shfl_xor(best, off, 64);
      int   oc = __shfl_xor(bcol, off, 64);
      if (ov > best || (ov == best && oc < bcol)) { best = ov; bcol = oc; }
    }
    if (lane == 0) out[sel] = bcol;
    int kill = ((bcol & 63) == lane) ? (bcol >> 6) : 32;
    #pragma unroll
    for (int t = 0; t < 32; ++t) if (t == kill) vals[t] = -INFINITY;
  }
}

// ---- layer 1 pass0: geometry + conv1 (BIT-FROZEN chain) + stats
// + f64 hmax/hmin store; writes R1/R2. ----
__global__ __launch_bounds__(64) void l1_p0(
    const float* __restrict__ x, const float* __restrict__ nrm,
    const float* __restrict__ w1, const int* __restrict__ idx1,
    double* __restrict__ sS, double* __restrict__ sQ,
    double* __restrict__ hmx1, double* __restrict__ hmn1,
    float* __restrict__ outR1, float* __restrict__ outR2) {
  int p = blockIdx.x;
  int tid = threadIdx.x;
  int b = p >> 11, n = p & (N - 1);
  __shared__ float  wl[C1 * 9];
  __shared__ double rotd[K][3];
  __shared__ double fld[K][9];
  for (int i = tid; i < C1 * 9; i += 64) wl[i] = w1[i];
  const float* xb = x + (size_t)b * N * 3;
  double nx = nrm[(size_t)p*3], ny = nrm[(size_t)p*3+1], nz = nrm[(size_t)p*3+2];
  double vx = ny, vy = -nx;
  double s = 1.0 / fmax(1.0 + nz, 1e-8);
  double vxy = vx * vy;
  double R1v[9];
  R1v[0] = 1.0 - s*(vy*vy); R1v[1] = s*vxy;           R1v[2] = vy;
  R1v[3] = s*vxy;           R1v[4] = 1.0 - s*(vx*vx); R1v[5] = -vx;
  R1v[6] = -vy;             R1v[7] = vx;              R1v[8] = 1.0 - s*(vx*vx + vy*vy);
  double xi0 = xb[(size_t)n*3], xi1 = xb[(size_t)n*3+1], xi2 = xb[(size_t)n*3+2];
  if (tid < K) {
    int j = idx1[(size_t)p*K + tid];
    double d0 = (double)xb[(size_t)j*3]   - xi0;
    double d1 = (double)xb[(size_t)j*3+1] - xi1;
    double d2 = (double)xb[(size_t)j*3+2] - xi2;
    rotd[tid][0] = R1v[0]*d0 + R1v[1]*d1 + R1v[2]*d2;
    rotd[tid][1] = R1v[3]*d0 + R1v[4]*d1 + R1v[5]*d2;
    rotd[tid][2] = R1v[6]*d0 + R1v[7]*d1 + R1v[8]*d2;
  }
  __syncthreads();
  double mx = 0.0, my = 0.0;
  #pragma unroll
  for (int k = 0; k < K; ++k) { mx += rotd[k][0]; my += rotd[k][1]; }
  mx /= 20.0; my /= 20.0;
  double r = sqrt(mx*mx + my*my);
  double ct = 1.0, st = 0.0;
  if (r > 0.0) { ct = mx / r; st = my / r; }   // cos/sin of atan2(my,mx)
  if (tid < K) {
    double r0 = rotd[tid][0], r1 = rotd[tid][1], r2 = rotd[tid][2];
    double a0 = ct*r0 + st*r1;
    double a1 = ct*r1 - st*r0;
    fld[tid][0] = a0;  fld[tid][1] = a1;   fld[tid][2] = r2;
    fld[tid][3] = a0;  fld[tid][4] = -a1;  fld[tid][5] = r2;   // xz-mirror
    fld[tid][6] = xi0; fld[tid][7] = xi1;  fld[tid][8] = xi2;  // x_rep
  }
  if (tid == 0) {
    float* o1 = outR1 + (size_t)p * 9;
    #pragma unroll
    for (int i = 0; i < 9; ++i) o1[i] = (float)R1v[i];
    float* o2 = outR2 + (size_t)p * 9;
    o2[0] = (float)ct;  o2[1] = (float)st; o2[2] = 0.f;
    o2[3] = (float)-st; o2[4] = (float)ct; o2[5] = 0.f;
    o2[6] = 0.f;        o2[7] = 0.f;       o2[8] = 1.f;
  }
  __syncthreads();
  int o = tid;
  double sum = 0., sq = 0., hmx = -INFINITY, hmn = INFINITY;
  #pragma unroll
  for (int k = 0; k < K; ++k) {
    double h = 0.;
    #pragma unroll
    for (int c = 0; c < 9; ++c) h = fma((double)wl[o*9 + c], fld[k][c], h);
    sum += h; sq += h*h;
    hmx = fmax(hmx, h); hmn = fmin(hmn, h);
  }
  hmx1[(size_t)p*C1 + o] = hmx;
  hmn1[(size_t)p*C1 + o] = hmn;
  int slice = p & (NSLICE - 1);
  atomicAdd(&sS[slice*C3 + o], sum);
  atomicAdd(&sQ[slice*C3 + o], sq);
}

// ---- layer 1 pass1 (light): BN+LReLU at h extremes (monotone => bit-exact
// same as the per-k fmax) -> x1d (f64) + out448. ----
__global__ __launch_bounds__(256) void l1_p1_light(
    const double* __restrict__ hmx1, const double* __restrict__ hmn1,
    const double* __restrict__ mid, const float* __restrict__ g1,
    const float* __restrict__ b1,
    double* __restrict__ x1d, float* __restrict__ out448) {
  int i = blockIdx.x * 256 + threadIdx.x;   // grid = B*N*C1/256
  int p = i >> 6, o = i & 63;
  double m = mid[o], is = mid[C3 + o];
  double g = g1[o], bb = b1[o];
  double y1 = ((hmx1[i] - m) * is) * g + bb;
  y1 = y1 > 0.0 ? y1 : 0.2 * y1;
  double y2 = ((hmn1[i] - m) * is) * g + bb;
  y2 = y2 > 0.0 ? y2 : 0.2 * y2;
  double mxv = fmax(y1, y2);
  x1d[i] = mxv;
  out448[(size_t)p*448 + o] = (float)mxv;
}

// ---- conv2 core: r12-proven LDS op sequence, 128 threads (BIT-FROZEN) ----
__device__ __forceinline__ void conv2_core(const double* __restrict__ x1d,
                                           const int* __restrict__ idx,
                                           const float* __restrict__ w,
                                           int p, int tid, double (&acc)[K]) {
  int b = p >> 11;
  __shared__ double difL[K][C1];
  __shared__ double xiL[C1];
  __shared__ int jidx[K];
  if (tid < K) jidx[tid] = idx[(size_t)p*K + tid];
  if (tid < C1) xiL[tid] = x1d[(size_t)p*C1 + tid];
  __syncthreads();
  #pragma unroll 1
  for (int i = tid; i < K*C1; i += 128) {
    int k = i >> 6, c = i & 63;
    difL[k][c] = x1d[((size_t)b*N + jidx[k])*C1 + c] - xiL[c];
  }
  __syncthreads();
  const float* wr = w + (size_t)tid * (2*C1);
  #pragma unroll
  for (int k = 0; k < K; ++k) acc[k] = 0.0;
  // phase 1: diff operand, c ascending per acc
  #pragma unroll
  for (int c0 = 0; c0 < C1; c0 += 16) {
    double wd[16];
    #pragma unroll
    for (int i = 0; i < 16; ++i) wd[i] = (double)wr[c0+i];
    #pragma unroll
    for (int k = 0; k < K; ++k) {
      #pragma unroll
      for (int i = 0; i < 16; ++i) acc[k] = fma(wd[i], difL[k][c0+i], acc[k]);
    }
  }
  // phase 2: x_rep operand, c ascending per acc
  #pragma unroll
  for (int c0 = 0; c0 < C1; c0 += 16) {
    double wd[16], xiv[16];
    #pragma unroll
    for (int i = 0; i < 16; ++i) { wd[i] = (double)wr[C1+c0+i]; xiv[i] = xiL[c0+i]; }
    #pragma unroll
    for (int k = 0; k < K; ++k) {
      #pragma unroll
      for (int i = 0; i < 16; ++i) acc[k] = fma(wd[i], xiv[i], acc[k]);
    }
  }
}

// ---- conv2 pass0: conv ONCE + stats + hmax/hmin (f64) store (r15-proven) ----
__global__ __launch_bounds__(128, 1) void conv2_p0(
    const double* __restrict__ x1d, const int* __restrict__ idx,
    const float* __restrict__ w,
    double* __restrict__ sS, double* __restrict__ sQ,
    double* __restrict__ hmx2, double* __restrict__ hmn2) {
  int p = blockIdx.x;
  int tid = threadIdx.x;
  double acc[K];
  conv2_core(x1d, idx, w, p, tid, acc);
  double sum = 0., sq = 0., hmx = -INFINITY, hmn = INFINITY;
  #pragma unroll
  for (int k = 0; k < K; ++k) {
    sum += acc[k]; sq += acc[k]*acc[k];
    hmx = fmax(hmx, acc[k]); hmn = fmin(hmn, acc[k]);
  }
  hmx2[(size_t)p*C2 + tid] = hmx;
  hmn2[(size_t)p*C2 + tid] = hmn;
  int slice = p & (NSLICE - 1);
  atomicAdd(&sS[slice*C3 + tid], sum);
  atomicAdd(&sQ[slice*C3 + tid], sq);
}

// ---- conv2 pass1 (light): BN+LReLU at h extremes (monotone => exact) ----
__global__ __launch_bounds__(256) void conv2_p1_light(
    const double* __restrict__ hmx2, const double* __restrict__ hmn2,
    const double* __restrict__ mid, const float* __restrict__ gam,
    const float* __restrict__ bet,
    double* __restrict__ x2d, float* __restrict__ out448) {
  int i = blockIdx.x * 256 + threadIdx.x;   // grid = B*N*C2/256
  int p = i >> 7, o = i & 127;
  double m = mid[o], is = mid[C3 + o];
  double g = gam[o], bb = bet[o];
  double y1 = ((hmx2[i] - m) * is) * g + bb;
  y1 = y1 > 0.0 ? y1 : 0.2 * y1;
  double y2 = ((hmn2[i] - m) * is) * g + bb;
  y2 = y2 > 0.0 ? y2 : 0.2 * y2;
  double mxv = fmax(y1, y2);
  x2d[i] = mxv;
  out448[(size_t)p*448 + C1 + o] = (float)mxv;
}

// ---- conv3 pass0: r12-proven skeleton (256 thr, acc[K], VGPR~80) — conv
// ONCE + stats + f32 hmax/hmin store (no h3 buffer at all). ----
__global__ __launch_bounds__(256, 1) void conv3_p0(
    const float* __restrict__ x2f, const int* __restrict__ idx,
    const float* __restrict__ w,
    double* __restrict__ sS, double* __restrict__ sQ,
    float* __restrict__ hmx3, float* __restrict__ hmn3) {
  int p = blockIdx.x;
  int tid = threadIdx.x;
  int b = p >> 11;
  __shared__ float xjL[K][C2];
  __shared__ float xiL[C2];
  __shared__ int jidx[K];
  if (tid < K) jidx[tid] = idx[(size_t)p*K + tid];
  if (tid < C2) xiL[tid] = x2f[(size_t)p*C2 + tid];
  __syncthreads();
  #pragma unroll 1
  for (int i = tid; i < K*C2; i += 256) {
    int k = i >> 7, c = i & 127;
    xjL[k][c] = x2f[((size_t)b*N + jidx[k])*C2 + c];
  }
  __syncthreads();
  const float* wr = w + (size_t)tid * (2*C2);
  float base = 0.f;
  #pragma unroll
  for (int c0 = 0; c0 < C2; c0 += 32) {
    #pragma unroll
    for (int i = 0; i < 32; ++i)
      base = fmaf(wr[C2+c0+i] - wr[c0+i], xiL[c0+i], base);
  }
  float acc[K];
  #pragma unroll
  for (int k = 0; k < K; ++k) acc[k] = base;
  #pragma unroll
  for (int c0 = 0; c0 < C2; c0 += 32) {
    float wd[32];
    #pragma unroll
    for (int i = 0; i < 32; ++i) wd[i] = wr[c0+i];
    #pragma unroll
    for (int k = 0; k < K; ++k) {
      #pragma unroll
      for (int i = 0; i < 32; ++i) acc[k] = fmaf(wd[i], xjL[k][c0+i], acc[k]);
    }
  }
  double sum = 0., sq = 0.;
  float hmx = -INFINITY, hmn = INFINITY;
  #pragma unroll
  for (int k = 0; k < K; ++k) {
    double h = (double)acc[k];
    sum += h; sq += h*h;
    hmx = fmaxf(hmx, acc[k]); hmn = fminf(hmn, acc[k]);
  }
  hmx3[(size_t)p*C3 + tid] = hmx;
  hmn3[(size_t)p*C3 + tid] = hmn;
  int slice = p & (NSLICE - 1);
  atomicAdd(&sS[slice*C3 + tid], sum);
  atomicAdd(&sQ[slice*C3 + tid], sq);
}

// ---- conv3 pass1 (light): BN+LReLU at extremes, fmax -> out ----
__global__ __launch_bounds__(256) void conv3_p1_light(
    const float* __restrict__ hmx3, const float* __restrict__ hmn3,
    const double* __restrict__ mid, const float* __restrict__ gam,
    const float* __restrict__ bet, float* __restrict__ out448) {
  int i = blockIdx.x * 256 + threadIdx.x;   // grid = B*N*C3/256
  int p = i >> 8, o = i & 255;
  float m = (float)mid[o], is = (float)mid[C3 + o];
  float g = gam[o], bb = bet[o];
  float y1 = (hmx3[i] - m) * is * g + bb;
  y1 = y1 > 0.f ? y1 : 0.2f * y1;
  float y2 = (hmn3[i] - m) * is * g + bb;
  y2 = y2 > 0.f ? y2 : 0.2f * y2;
  out448[(size_t)p*448 + C1 + C2 + o] = fmaxf(y1, y2);
}

// ---- finalize BN stats (f64) ----
__global__ void finalize_stats(const double* __restrict__ sS, const double* __restrict__ sQ,
                               double* __restrict__ mid, int C) {
  int o = threadIdx.x;
  if (o >= C) return;
  double s = 0., q = 0.;
  for (int i = 0; i < NSLICE; ++i) { s += sS[i*C3 + o]; q += sQ[i*C3 + o]; }
  double m = s / COUNT;
  double v = q / COUNT - m*m;
  mid[o] = m;
  mid[C3 + o] = 1.0 / sqrt(v + BNEPS);
}

} // namespace

extern "C" void kernel_launch(void* const* d_in, const int* in_sizes, int n_in,
                              void* d_out, int out_size, void* d_ws, size_t ws_size,
                              hipStream_t stream) {
  (void)in_sizes; (void)n_in; (void)out_size; (void)ws_size;
  const float* x   = (const float*)d_in[0];
  const float* nrm = (const float*)d_in[1];
  const float* w1  = (const float*)d_in[2];
  const float* g1  = (const float*)d_in[3];
  const float* b1  = (const float*)d_in[4];
  const float* w2  = (const float*)d_in[5];
  const float* g2  = (const float*)d_in[6];
  const float* b2  = (const float*)d_in[7];
  const float* w3  = (const float*)d_in[8];
  const float* g3  = (const float*)d_in[9];
  const float* b3  = (const float*)d_in[10];
  float* out = (float*)d_out;
  char*  ws  = (char*)d_ws;

  int*    idx1 = (int*)(ws + OFF_IDX1);
  int*    idx2 = (int*)(ws + OFF_IDX2);
  double* x1d  = (double*)(ws + OFF_X1D);
  double* x2d  = (double*)(ws + OFF_X2D);
  double* sS   = (double*)(ws + OFF_STATS);
  double* sQ   = sS + (size_t)NSLICE * C3;
  double* mid  = (double*)(ws + OFF_MI);
  float*  x2f  = (float*)(ws + OFF_X2F);
  float*  xx2f = (float*)(ws + OFF_XX2F);
  char*   big  = ws + OFF_BIG;
  double* hmx1 = (double*)big;                                   // l1_p0..p1
  double* hmn1 = hmx1 + (size_t)B*N*C1;
  double* hmx2 = (double*)big;                                   // conv2_p0..p1
  double* hmn2 = hmx2 + (size_t)B*N*C2;
  float*  dist = (float*)big;                                    // dist..knn_feat
  float*  hmx3 = (float*)big;                                    // conv3_p0..p1
  float*  hmn3 = hmx3 + (size_t)B*N*C3;

  float* outR1 = out + (size_t)B * N * 448;
  float* outR2 = outR1 + (size_t)B * N * 9;

  // kNN1 — numpy-f32-faithful values, wave-parallel selection
  knn_xyz_wave<<<B*N/4, 256, 0, stream>>>(x, idx1);

  // layer 1: geometry+conv once (bit-frozen chain) + extremes; light BN finish
  hipMemsetAsync(sS, 0, (size_t)2*NSLICE*C3*sizeof(double), stream);
  l1_p0<<<B*N, 64, 0, stream>>>(x, nrm, w1, idx1, sS, sQ, hmx1, hmn1, outR1, outR2);
  finalize_stats<<<1, C3, 0, stream>>>(sS, sQ, mid, C1);
  l1_p1_light<<<B*N*C1/256, 256, 0, stream>>>(hmx1, hmn1, mid, g1, b1, x1d, out);

  // layer 2: conv once (bit-frozen core) + extremes; light BN finish
  hipMemsetAsync(sS, 0, (size_t)2*NSLICE*C3*sizeof(double), stream);
  conv2_p0<<<B*N, 128, 0, stream>>>(x1d, idx1, w2, sS, sQ, hmx2, hmn2);
  finalize_stats<<<1, C3, 0, stream>>>(sS, sQ, mid, C2);
  conv2_p1_light<<<B*N*C2/256, 256, 0, stream>>>(hmx2, hmn2, mid, g2, b2, x2d, out);

  // kNN2 — numpy-f32-faithful, all batches fused; wave-parallel coalesced top-k
  xx2f_kernel<<<B*N/64, 64, 0, stream>>>(x2d, x2f, xx2f);
  dist_f32_kernel<<<dim3(N/64, N/64, B), 256, 0, stream>>>(x2f, xx2f, dist);
  knn_feat_wave<<<B*N/4, 256, 0, stream>>>(dist, idx2);

  // layer 3: conv once (f32, r12 skeleton) + extremes; light BN finish
  hipMemsetAsync(sS, 0, (size_t)2*NSLICE*C3*sizeof(double), stream);
  conv3_p0<<<B*N, 256, 0, stream>>>(x2f, idx2, w3, sS, sQ, hmx3, hmn3);
  finalize_stats<<<1, C3, 0, stream>>>(sS, sQ, mid, C3);
  conv3_p1_light<<<B*N*C3/256, 256, 0, stream>>>(hmx3, hmn3, mid, g3, b3, out);
}